// Round 15
// baseline (934.828 us; speedup 1.0000x reference)
//
#include <hip/hip_runtime.h>
#include <stdint.h>

#define FIN 256
#define FHID 128
#define BN_EPS 1e-3f

#ifndef USE_GLL
#if defined(__has_builtin)
#if __has_builtin(__builtin_amdgcn_global_load_lds)
#define USE_GLL 1
#else
#define USE_GLL 0
#endif
#else
#define USE_GLL 0
#endif
#endif

typedef short bf16x8 __attribute__((ext_vector_type(8)));
typedef float f32x4 __attribute__((ext_vector_type(4)));

__device__ inline short f2bf(float f) {
    unsigned u = __float_as_uint(f);
    unsigned r = (u + 0x7FFFu + ((u >> 16) & 1u)) >> 16;   // RNE
    return (short)r;
}
__device__ inline float bflo(unsigned v) { return __uint_as_float(v << 16); }
__device__ inline float bfhi(unsigned v) { return __uint_as_float(v & 0xFFFF0000u); }
__device__ inline float bf2f(short s) {
    return __uint_as_float(((unsigned)(unsigned short)s) << 16);
}

#define DEG_SCALE 131072.0f          // 2^17 fixed point
#define DEG_INV   (1.0f / 131072.0f)

// ------- hist (HB fine-grained blocks) || W0,W1 -> bf16 transposed ----------
__global__ __launch_bounds__(256) void k_histprep(const int* __restrict__ ei, int E,
                                                  int HB, int CHUNKH, int nbuk,
                                                  unsigned* __restrict__ bcnt,
                                                  const float* __restrict__ W0,
                                                  const float* __restrict__ W1,
                                                  short* __restrict__ Wt0,
                                                  short* __restrict__ Wt1) {
    __shared__ unsigned hist[1024];
    if ((int)blockIdx.x < HB) {
        for (int i = threadIdx.x; i < nbuk; i += 256) hist[i] = 0;
        __syncthreads();
        const int e0 = blockIdx.x * CHUNKH;
        const int e1 = min(e0 + CHUNKH, E);
        for (int e = e0 + threadIdx.x; e < e1; e += 256)
            atomicAdd(&hist[ei[E + e] >> 7], 1u);
        __syncthreads();
        for (int k = threadIdx.x; k < nbuk; k += 256)
            bcnt[(size_t)blockIdx.x * nbuk + k] = hist[k];
    } else {
        int idx = ((int)blockIdx.x - HB) * 256 + threadIdx.x;
        if (idx < 32768) {            // W0: [256][128] -> Wt0 [128][256]
            int n = idx >> 8, k = idx & 255;
            Wt0[idx] = f2bf(W0[k * 128 + n]);
        } else {
            int j = idx - 32768;      // W1: [128][128] -> Wt1 [128][128]
            if (j < 16384) {
                int n = j >> 7, k = j & 127;
                Wt1[j] = f2bf(W1[k * 128 + n]);
            }
        }
    }
}

// ---------------- gemm0 compute body (LDS-staged, swizzled) ----------------
__device__ __forceinline__ void gemm0_body(int bid, float* xs,
                                           const float* __restrict__ X,
                                           const short* __restrict__ Wt,
                                           short* __restrict__ H, int nrows) {
    const int t = threadIdx.x;
    const int lane = t & 63;
    const int w = t >> 6;
    const int r0 = bid * 32;
    const int l15 = lane & 15;
    const int q = lane >> 4;

#pragma unroll
    for (int i = 0; i < 8; i++) {
        const int row = w * 8 + i;
        int grow = r0 + row; if (grow >= nrows) grow = nrows - 1;
        const char* gsrc = (const char*)(X + (size_t)grow * 256);
        const int swz = (row & 7) << 4;
#if USE_GLL
        __builtin_amdgcn_global_load_lds(gsrc + ((lane * 16) ^ swz),
                                         xs + row * 256, 16, 0, 0);
#else
        const float4 v = *reinterpret_cast<const float4*>(gsrc + ((lane * 16) ^ swz));
        *reinterpret_cast<float4*>((char*)xs + row * 1024 + lane * 16) = v;
#endif
    }
    __syncthreads();

    const int n0 = w * 32;
    const int swzr = (l15 & 7) << 4;

    f32x4 acc[2][2];
#pragma unroll
    for (int mf = 0; mf < 2; mf++)
#pragma unroll
        for (int nf = 0; nf < 2; nf++)
#pragma unroll
            for (int r = 0; r < 4; r++) acc[mf][nf][r] = 0.0f;

#pragma unroll
    for (int ks = 0; ks < 8; ks++) {
        const int cb = ks * 128 + q * 32;
        bf16x8 a[2];
#pragma unroll
        for (int mf = 0; mf < 2; mf++) {
            const char* rb = (const char*)xs + (size_t)(mf * 16 + l15) * 1024;
            const float4 u0 = *reinterpret_cast<const float4*>(rb + (cb ^ swzr));
            const float4 u1 = *reinterpret_cast<const float4*>(rb + ((cb + 16) ^ swzr));
            bf16x8 tt;
            tt[0] = f2bf(u0.x); tt[1] = f2bf(u0.y); tt[2] = f2bf(u0.z); tt[3] = f2bf(u0.w);
            tt[4] = f2bf(u1.x); tt[5] = f2bf(u1.y); tt[6] = f2bf(u1.z); tt[7] = f2bf(u1.w);
            a[mf] = tt;
        }
        const bf16x8 b0 = *reinterpret_cast<const bf16x8*>(
            Wt + (size_t)(n0 + l15) * 256 + ks * 32 + q * 8);
        const bf16x8 b1 = *reinterpret_cast<const bf16x8*>(
            Wt + (size_t)(n0 + 16 + l15) * 256 + ks * 32 + q * 8);
        acc[0][0] = __builtin_amdgcn_mfma_f32_16x16x32_bf16(a[0], b0, acc[0][0], 0, 0, 0);
        acc[1][0] = __builtin_amdgcn_mfma_f32_16x16x32_bf16(a[1], b0, acc[1][0], 0, 0, 0);
        acc[0][1] = __builtin_amdgcn_mfma_f32_16x16x32_bf16(a[0], b1, acc[0][1], 0, 0, 0);
        acc[1][1] = __builtin_amdgcn_mfma_f32_16x16x32_bf16(a[1], b1, acc[1][1], 0, 0, 0);
    }

#pragma unroll
    for (int mf = 0; mf < 2; mf++) {
        const int rbase = r0 + mf * 16 + (lane >> 4) * 4;
#pragma unroll
        for (int r = 0; r < 4; r++) {
            const int row = rbase + r;
            if (row < nrows) {
#pragma unroll
                for (int nf = 0; nf < 2; nf++)
                    H[(size_t)row * 128 + n0 + nf * 16 + l15] = f2bf(acc[mf][nf][r]);
            }
        }
    }
}

// ------ fused: phaseC bucket-scatter (blocks < CBC)  ||  gemm0 (rest) -------
__global__ __launch_bounds__(256) void k_phaseCG(const int* __restrict__ ei,
                                                 const float* __restrict__ ew,
                                                 int E, int CHUNKC, int nbuk, int sub,
                                                 const unsigned* __restrict__ bcnt,
                                                 const unsigned* __restrict__ bbase,
                                                 int2* __restrict__ recs_mid,
                                                 int CBC,
                                                 const float* __restrict__ X,
                                                 const short* __restrict__ Wt,
                                                 short* __restrict__ H, int nrows) {
    __shared__ float xs[8192];   // 32KB; phaseC aliases first 4KB as cursors
    if ((int)blockIdx.x < CBC) {
        unsigned* curs = (unsigned*)xs;
        const int b = blockIdx.x;
        for (int k = threadIdx.x; k < nbuk; k += 256)
            curs[k] = bbase[k] + bcnt[(size_t)(b * sub) * nbuk + k];
        __syncthreads();
        const int e0 = b * CHUNKC;
        const int e1 = min(e0 + CHUNKC, E);
        for (int base = e0; base < e1; base += 1024) {
            const int e = base + threadIdx.x * 4;
            if (e + 3 < e1) {
                const int4 s4 = *reinterpret_cast<const int4*>(ei + e);
                const int4 d4 = *reinterpret_cast<const int4*>(ei + E + e);
                const float4 w4 = *reinterpret_cast<const float4*>(ew + e);
                unsigned p0 = atomicAdd(&curs[d4.x >> 7], 1u);
                recs_mid[p0] = make_int2(s4.x | ((d4.x & 127) << 17), __float_as_int(w4.x));
                unsigned p1 = atomicAdd(&curs[d4.y >> 7], 1u);
                recs_mid[p1] = make_int2(s4.y | ((d4.y & 127) << 17), __float_as_int(w4.y));
                unsigned p2 = atomicAdd(&curs[d4.z >> 7], 1u);
                recs_mid[p2] = make_int2(s4.z | ((d4.z & 127) << 17), __float_as_int(w4.z));
                unsigned p3 = atomicAdd(&curs[d4.w >> 7], 1u);
                recs_mid[p3] = make_int2(s4.w | ((d4.w & 127) << 17), __float_as_int(w4.w));
            } else {
#pragma unroll
                for (int j = 0; j < 4; j++) {
                    const int ee = e + j;
                    if (ee < e1) {
                        int src = ei[ee];
                        int dst = ei[E + ee];
                        unsigned pos = atomicAdd(&curs[dst >> 7], 1u);
                        recs_mid[pos] = make_int2(src | ((dst & 127) << 17),
                                                  __float_as_int(ew[ee]));
                    }
                }
            }
        }
    } else {
        gemm0_body((int)blockIdx.x - CBC, xs, X, Wt, H, nrows);
    }
}

// ---------------- GEMM1: bf16 agg staged to LDS + BN0+ReLU fused ------------
__global__ __launch_bounds__(256) void k_gemm1(const short* __restrict__ X,
                                               const short* __restrict__ Wt,
                                               const float* __restrict__ prm,
                                               short* __restrict__ H, int nrows) {
    __shared__ short xs[4096];   // 8KB
    const int t = threadIdx.x;
    const int lane = t & 63;
    const int w = t >> 6;
    const int r0 = blockIdx.x * 32;
    const int l15 = lane & 15;
    const int q = lane >> 4;

#pragma unroll
    for (int j = 0; j < 2; j++) {
        const int rbase = w * 8 + j * 4;
        const int row = rbase + q;
        int grow = r0 + row; if (grow >= nrows) grow = nrows - 1;
        const char* gsrc = (const char*)(X + (size_t)grow * 128);
        const int swz = (row & 7) << 4;
#if USE_GLL
        __builtin_amdgcn_global_load_lds(gsrc + (((lane & 15) * 16) ^ swz),
                                         xs + rbase * 128, 16, 0, 0);
#else
        const uint4 v = *reinterpret_cast<const uint4*>(gsrc + (((lane & 15) * 16) ^ swz));
        *reinterpret_cast<uint4*>((char*)xs + rbase * 256 + lane * 16) = v;
#endif
    }
    __syncthreads();

    const int n0 = w * 32;
    const int swzr = (l15 & 7) << 4;

    f32x4 acc[2][2];
#pragma unroll
    for (int mf = 0; mf < 2; mf++)
#pragma unroll
        for (int nf = 0; nf < 2; nf++)
#pragma unroll
            for (int r = 0; r < 4; r++) acc[mf][nf][r] = 0.0f;

#pragma unroll
    for (int ks = 0; ks < 4; ks++) {
        const int kb = ks * 32 + q * 8;
        const int cb = ks * 64 + q * 16;
        const float4 sc0 = *reinterpret_cast<const float4*>(prm + kb);
        const float4 sc1 = *reinterpret_cast<const float4*>(prm + kb + 4);
        const float4 sh0 = *reinterpret_cast<const float4*>(prm + 128 + kb);
        const float4 sh1 = *reinterpret_cast<const float4*>(prm + 128 + kb + 4);
        bf16x8 a[2];
#pragma unroll
        for (int mf = 0; mf < 2; mf++) {
            const char* rb = (const char*)xs + (size_t)(mf * 16 + l15) * 256;
            const bf16x8 ar = *reinterpret_cast<const bf16x8*>(rb + (cb ^ swzr));
            bf16x8 tt;
            tt[0] = f2bf(fmaxf(bf2f(ar[0]) * sc0.x + sh0.x, 0.f));
            tt[1] = f2bf(fmaxf(bf2f(ar[1]) * sc0.y + sh0.y, 0.f));
            tt[2] = f2bf(fmaxf(bf2f(ar[2]) * sc0.z + sh0.z, 0.f));
            tt[3] = f2bf(fmaxf(bf2f(ar[3]) * sc0.w + sh0.w, 0.f));
            tt[4] = f2bf(fmaxf(bf2f(ar[4]) * sc1.x + sh1.x, 0.f));
            tt[5] = f2bf(fmaxf(bf2f(ar[5]) * sc1.y + sh1.y, 0.f));
            tt[6] = f2bf(fmaxf(bf2f(ar[6]) * sc1.z + sh1.z, 0.f));
            tt[7] = f2bf(fmaxf(bf2f(ar[7]) * sc1.w + sh1.w, 0.f));
            a[mf] = tt;
        }
        const bf16x8 b0 = *reinterpret_cast<const bf16x8*>(
            Wt + (size_t)(n0 + l15) * 128 + kb);
        const bf16x8 b1 = *reinterpret_cast<const bf16x8*>(
            Wt + (size_t)(n0 + 16 + l15) * 128 + kb);
        acc[0][0] = __builtin_amdgcn_mfma_f32_16x16x32_bf16(a[0], b0, acc[0][0], 0, 0, 0);
        acc[1][0] = __builtin_amdgcn_mfma_f32_16x16x32_bf16(a[1], b0, acc[1][0], 0, 0, 0);
        acc[0][1] = __builtin_amdgcn_mfma_f32_16x16x32_bf16(a[0], b1, acc[0][1], 0, 0, 0);
        acc[1][1] = __builtin_amdgcn_mfma_f32_16x16x32_bf16(a[1], b1, acc[1][1], 0, 0, 0);
    }

#pragma unroll
    for (int mf = 0; mf < 2; mf++) {
        const int rbase = r0 + mf * 16 + (lane >> 4) * 4;
#pragma unroll
        for (int r = 0; r < 4; r++) {
            const int row = rbase + r;
            if (row < nrows) {
#pragma unroll
                for (int nf = 0; nf < 2; nf++)
                    H[(size_t)row * 128 + n0 + nf * 16 + l15] = f2bf(acc[mf][nf][r]);
            }
        }
    }
}

// -------- phase B: per-bucket scan of HB block counts (4/thread) ------------
__global__ __launch_bounds__(256) void k_phaseB(unsigned* __restrict__ bcnt,
                                                unsigned* __restrict__ btotal,
                                                int HB, int nbuk) {
    __shared__ unsigned lds[256];
    const int k = blockIdx.x;
    const int t = threadIdx.x;
    unsigned v[4];
    unsigned s = 0;
#pragma unroll
    for (int i = 0; i < 4; i++) {
        int j = t * 4 + i;
        v[i] = (j < HB) ? bcnt[(size_t)j * nbuk + k] : 0;
        s += v[i];
    }
    lds[t] = s;
    __syncthreads();
    for (int off = 1; off < 256; off <<= 1) {
        unsigned add = (t >= off) ? lds[t - off] : 0;
        __syncthreads();
        lds[t] += add;
        __syncthreads();
    }
    unsigned run = lds[t] - s;
#pragma unroll
    for (int i = 0; i < 4; i++) {
        int j = t * 4 + i;
        if (j < HB) bcnt[(size_t)j * nbuk + k] = run;
        run += v[i];
    }
    if (t == 255) btotal[k] = lds[255];
}

// ---------------- bucket base scan (single block) ----------------
__global__ __launch_bounds__(256) void k_bsum(const unsigned* __restrict__ btotal,
                                              unsigned* __restrict__ bbase,
                                              int nbuk, int E) {
    __shared__ unsigned lds[256];
    const int t = threadIdx.x;
    unsigned v[4];
    unsigned s = 0;
#pragma unroll
    for (int i = 0; i < 4; i++) {
        int j = t * 4 + i;
        v[i] = (j < nbuk) ? btotal[j] : 0;
        s += v[i];
    }
    lds[t] = s;
    __syncthreads();
    for (int off = 1; off < 256; off <<= 1) {
        unsigned add = (t >= off) ? lds[t - off] : 0;
        __syncthreads();
        lds[t] += add;
        __syncthreads();
    }
    unsigned run = lds[t] - s;
#pragma unroll
    for (int i = 0; i < 4; i++) {
        int j = t * 4 + i;
        if (j < nbuk) bbase[j] = run;
        run += v[i];
    }
    if (t == 255) bbase[nbuk] = (unsigned)E;
}

// ---- phase D: per-bucket dst sort, dinv, rowptr, recs (ew*dinv_dst) --------
__global__ __launch_bounds__(256) void k_phaseD(const int2* __restrict__ recs_mid,
                                                const unsigned* __restrict__ bbase,
                                                float* __restrict__ dinv,
                                                int* __restrict__ rowptr,
                                                int2* __restrict__ recs,
                                                int n, int E) {
    __shared__ unsigned cnt[128], wsum[128], rank[128], sc[128], base[128];
    __shared__ float dloc[128];
    const int k = blockIdx.x;
    const int t = threadIdx.x;
    if (t < 128) { cnt[t] = 0; wsum[t] = 0; rank[t] = 0; }
    __syncthreads();
    const unsigned s0 = bbase[k], s1 = bbase[k + 1];
    for (unsigned i = s0 + t; i < s1; i += 256) {
        int2 r = recs_mid[i];
        int dl = (r.x >> 17) & 127;
        atomicAdd(&cnt[dl], 1u);
        atomicAdd(&wsum[dl], (unsigned)(__int_as_float(r.y) * DEG_SCALE));
    }
    __syncthreads();
    if (t < 128) sc[t] = cnt[t];
    __syncthreads();
    for (int off = 1; off < 128; off <<= 1) {
        unsigned add = (t < 128 && t >= off) ? sc[t - off] : 0;
        __syncthreads();
        if (t < 128) sc[t] += add;
        __syncthreads();
    }
    if (t < 128) {
        unsigned excl = sc[t] - cnt[t];
        base[t] = s0 + excl;
        int dst = k * 128 + t;
        if (dst < n) {
            float dg = (float)wsum[t] * DEG_INV + 1.0f;
            float dv = rsqrtf(dg);
            dloc[t] = dv;
            dinv[dst] = dv;
            rowptr[dst] = (int)(s0 + excl);
        }
    }
    if (k == 0 && t == 0) rowptr[n] = E;
    __syncthreads();
    for (unsigned i = s0 + t; i < s1; i += 256) {
        int2 r = recs_mid[i];
        int dl = (r.x >> 17) & 127;
        unsigned rr = atomicAdd(&rank[dl], 1u);
        float w2 = __int_as_float(r.y) * dloc[dl];     // ew * dinv[dst]
        recs[base[dl] + rr] = make_int2(r.x & 0x1FFFF, __float_as_int(w2));
    }
}

// --- gather + stats: per-WAVE dynamic 4-node chunks (no block barriers) -----
__global__ __launch_bounds__(256) void k_gather_stats(const short* __restrict__ h,
                                                      short* __restrict__ aggbf,
                                                      const int* __restrict__ rowptr,
                                                      const int2* __restrict__ recs,
                                                      const float* __restrict__ dinv,
                                                      const float* __restrict__ bias,
                                                      float* __restrict__ partial,
                                                      unsigned* __restrict__ ctr,
                                                      int n) {
    __shared__ float lsum[4][128], lsq[4][128];
    const int w = threadIdx.x >> 6;
    const int lane = threadIdx.x & 63;
    const int q3 = lane >> 4;            // quarter id
    const int f8 = (lane & 15) * 8;      // feature slice [f8, f8+8)
    const float4 bv0 = *reinterpret_cast<const float4*>(bias + f8);
    const float4 bv1 = *reinterpret_cast<const float4*>(bias + f8 + 4);
    float s[8], qq[8];
#pragma unroll
    for (int j = 0; j < 8; j++) { s[j] = 0.f; qq[j] = 0.f; }

    for (;;) {
        int nb = 0;
        if (lane == 0) nb = (int)atomicAdd(ctr, 4u);
        nb = __shfl(nb, 0);
        if (nb >= n) break;
        const int node = nb + q3;
        if (node < n) {
            float a[8];
#pragma unroll
            for (int j = 0; j < 8; j++) a[j] = 0.f;
            int e = rowptr[node];
            const int end = rowptr[node + 1];
            for (; e + 8 <= end; e += 8) {
                const int2 r0 = recs[e];
                const int2 r1 = recs[e + 1];
                const int2 r2 = recs[e + 2];
                const int2 r3 = recs[e + 3];
                const int2 r4 = recs[e + 4];
                const int2 r5 = recs[e + 5];
                const int2 r6 = recs[e + 6];
                const int2 r7 = recs[e + 7];
                const float d0 = dinv[r0.x];
                const float d1 = dinv[r1.x];
                const float d2 = dinv[r2.x];
                const float d3 = dinv[r3.x];
                const float d4 = dinv[r4.x];
                const float d5 = dinv[r5.x];
                const float d6 = dinv[r6.x];
                const float d7 = dinv[r7.x];
                const uint4 v0 = *reinterpret_cast<const uint4*>(h + (size_t)r0.x * 128 + f8);
                const uint4 v1 = *reinterpret_cast<const uint4*>(h + (size_t)r1.x * 128 + f8);
                const uint4 v2 = *reinterpret_cast<const uint4*>(h + (size_t)r2.x * 128 + f8);
                const uint4 v3 = *reinterpret_cast<const uint4*>(h + (size_t)r3.x * 128 + f8);
                const uint4 v4 = *reinterpret_cast<const uint4*>(h + (size_t)r4.x * 128 + f8);
                const uint4 v5 = *reinterpret_cast<const uint4*>(h + (size_t)r5.x * 128 + f8);
                const uint4 v6 = *reinterpret_cast<const uint4*>(h + (size_t)r6.x * 128 + f8);
                const uint4 v7 = *reinterpret_cast<const uint4*>(h + (size_t)r7.x * 128 + f8);
                const float w0 = __int_as_float(r0.y) * d0;
                const float w1 = __int_as_float(r1.y) * d1;
                const float w2 = __int_as_float(r2.y) * d2;
                const float w3 = __int_as_float(r3.y) * d3;
                const float w4 = __int_as_float(r4.y) * d4;
                const float w5 = __int_as_float(r5.y) * d5;
                const float w6 = __int_as_float(r6.y) * d6;
                const float w7 = __int_as_float(r7.y) * d7;
                a[0] += bflo(v0.x) * w0; a[1] += bfhi(v0.x) * w0;
                a[2] += bflo(v0.y) * w0; a[3] += bfhi(v0.y) * w0;
                a[4] += bflo(v0.z) * w0; a[5] += bfhi(v0.z) * w0;
                a[6] += bflo(v0.w) * w0; a[7] += bfhi(v0.w) * w0;
                a[0] += bflo(v1.x) * w1; a[1] += bfhi(v1.x) * w1;
                a[2] += bflo(v1.y) * w1; a[3] += bfhi(v1.y) * w1;
                a[4] += bflo(v1.z) * w1; a[5] += bfhi(v1.z) * w1;
                a[6] += bflo(v1.w) * w1; a[7] += bfhi(v1.w) * w1;
                a[0] += bflo(v2.x) * w2; a[1] += bfhi(v2.x) * w2;
                a[2] += bflo(v2.y) * w2; a[3] += bfhi(v2.y) * w2;
                a[4] += bflo(v2.z) * w2; a[5] += bfhi(v2.z) * w2;
                a[6] += bflo(v2.w) * w2; a[7] += bfhi(v2.w) * w2;
                a[0] += bflo(v3.x) * w3; a[1] += bfhi(v3.x) * w3;
                a[2] += bflo(v3.y) * w3; a[3] += bfhi(v3.y) * w3;
                a[4] += bflo(v3.z) * w3; a[5] += bfhi(v3.z) * w3;
                a[6] += bflo(v3.w) * w3; a[7] += bfhi(v3.w) * w3;
                a[0] += bflo(v4.x) * w4; a[1] += bfhi(v4.x) * w4;
                a[2] += bflo(v4.y) * w4; a[3] += bfhi(v4.y) * w4;
                a[4] += bflo(v4.z) * w4; a[5] += bfhi(v4.z) * w4;
                a[6] += bflo(v4.w) * w4; a[7] += bfhi(v4.w) * w4;
                a[0] += bflo(v5.x) * w5; a[1] += bfhi(v5.x) * w5;
                a[2] += bflo(v5.y) * w5; a[3] += bfhi(v5.y) * w5;
                a[4] += bflo(v5.z) * w5; a[5] += bfhi(v5.z) * w5;
                a[6] += bflo(v5.w) * w5; a[7] += bfhi(v5.w) * w5;
                a[0] += bflo(v6.x) * w6; a[1] += bfhi(v6.x) * w6;
                a[2] += bflo(v6.y) * w6; a[3] += bfhi(v6.y) * w6;
                a[4] += bflo(v6.z) * w6; a[5] += bfhi(v6.z) * w6;
                a[6] += bflo(v6.w) * w6; a[7] += bfhi(v6.w) * w6;
                a[0] += bflo(v7.x) * w7; a[1] += bfhi(v7.x) * w7;
                a[2] += bflo(v7.y) * w7; a[3] += bfhi(v7.y) * w7;
                a[4] += bflo(v7.z) * w7; a[5] += bfhi(v7.z) * w7;
                a[6] += bflo(v7.w) * w7; a[7] += bfhi(v7.w) * w7;
            }
            for (; e + 4 <= end; e += 4) {
                const int2 r0 = recs[e];
                const int2 r1 = recs[e + 1];
                const int2 r2 = recs[e + 2];
                const int2 r3 = recs[e + 3];
                const float d0 = dinv[r0.x];
                const float d1 = dinv[r1.x];
                const float d2 = dinv[r2.x];
                const float d3 = dinv[r3.x];
                const uint4 v0 = *reinterpret_cast<const uint4*>(h + (size_t)r0.x * 128 + f8);
                const uint4 v1 = *reinterpret_cast<const uint4*>(h + (size_t)r1.x * 128 + f8);
                const uint4 v2 = *reinterpret_cast<const uint4*>(h + (size_t)r2.x * 128 + f8);
                const uint4 v3 = *reinterpret_cast<const uint4*>(h + (size_t)r3.x * 128 + f8);
                const float w0 = __int_as_float(r0.y) * d0;
                const float w1 = __int_as_float(r1.y) * d1;
                const float w2 = __int_as_float(r2.y) * d2;
                const float w3 = __int_as_float(r3.y) * d3;
                a[0] += bflo(v0.x) * w0; a[1] += bfhi(v0.x) * w0;
                a[2] += bflo(v0.y) * w0; a[3] += bfhi(v0.y) * w0;
                a[4] += bflo(v0.z) * w0; a[5] += bfhi(v0.z) * w0;
                a[6] += bflo(v0.w) * w0; a[7] += bfhi(v0.w) * w0;
                a[0] += bflo(v1.x) * w1; a[1] += bfhi(v1.x) * w1;
                a[2] += bflo(v1.y) * w1; a[3] += bfhi(v1.y) * w1;
                a[4] += bflo(v1.z) * w1; a[5] += bfhi(v1.z) * w1;
                a[6] += bflo(v1.w) * w1; a[7] += bfhi(v1.w) * w1;
                a[0] += bflo(v2.x) * w2; a[1] += bfhi(v2.x) * w2;
                a[2] += bflo(v2.y) * w2; a[3] += bfhi(v2.y) * w2;
                a[4] += bflo(v2.z) * w2; a[5] += bfhi(v2.z) * w2;
                a[6] += bflo(v2.w) * w2; a[7] += bfhi(v2.w) * w2;
                a[0] += bflo(v3.x) * w3; a[1] += bfhi(v3.x) * w3;
                a[2] += bflo(v3.y) * w3; a[3] += bfhi(v3.y) * w3;
                a[4] += bflo(v3.z) * w3; a[5] += bfhi(v3.z) * w3;
                a[6] += bflo(v3.w) * w3; a[7] += bfhi(v3.w) * w3;
            }
            for (; e < end; e++) {
                const int2 r = recs[e];
                const float d = dinv[r.x];
                const uint4 v = *reinterpret_cast<const uint4*>(h + (size_t)r.x * 128 + f8);
                const float w0 = __int_as_float(r.y) * d;
                a[0] += bflo(v.x) * w0; a[1] += bfhi(v.x) * w0;
                a[2] += bflo(v.y) * w0; a[3] += bfhi(v.y) * w0;
                a[4] += bflo(v.z) * w0; a[5] += bfhi(v.z) * w0;
                a[6] += bflo(v.w) * w0; a[7] += bfhi(v.w) * w0;
            }
            const float di = dinv[node];
            const float sl = di * di;
            const uint4 hv = *reinterpret_cast<const uint4*>(h + (size_t)node * 128 + f8);
            float o[8];
            o[0] = a[0] + bflo(hv.x) * sl + bv0.x;
            o[1] = a[1] + bfhi(hv.x) * sl + bv0.y;
            o[2] = a[2] + bflo(hv.y) * sl + bv0.z;
            o[3] = a[3] + bfhi(hv.y) * sl + bv0.w;
            o[4] = a[4] + bflo(hv.z) * sl + bv1.x;
            o[5] = a[5] + bfhi(hv.z) * sl + bv1.y;
            o[6] = a[6] + bflo(hv.w) * sl + bv1.z;
            o[7] = a[7] + bfhi(hv.w) * sl + bv1.w;
            bf16x8 ob;
#pragma unroll
            for (int j = 0; j < 8; j++) ob[j] = f2bf(o[j]);
            *reinterpret_cast<bf16x8*>(aggbf + (size_t)node * 128 + f8) = ob;
#pragma unroll
            for (int j = 0; j < 8; j++) { s[j] += o[j]; qq[j] += o[j] * o[j]; }
        }
    }

#pragma unroll
    for (int j = 0; j < 8; j++) {
        s[j] += __shfl_xor(s[j], 16);  s[j] += __shfl_xor(s[j], 32);
        qq[j] += __shfl_xor(qq[j], 16); qq[j] += __shfl_xor(qq[j], 32);
    }
    if (q3 == 0) {
        *reinterpret_cast<float4*>(&lsum[w][f8]) = make_float4(s[0], s[1], s[2], s[3]);
        *reinterpret_cast<float4*>(&lsum[w][f8 + 4]) = make_float4(s[4], s[5], s[6], s[7]);
        *reinterpret_cast<float4*>(&lsq[w][f8]) = make_float4(qq[0], qq[1], qq[2], qq[3]);
        *reinterpret_cast<float4*>(&lsq[w][f8 + 4]) = make_float4(qq[4], qq[5], qq[6], qq[7]);
    }
    __syncthreads();
    const int t = threadIdx.x;
    if (t < 128) {
        float ps = lsum[0][t] + lsum[1][t] + lsum[2][t] + lsum[3][t];
        float pq = lsq[0][t] + lsq[1][t] + lsq[2][t] + lsq[3][t];
        partial[(size_t)blockIdx.x * 256 + t] = ps;
        partial[(size_t)blockIdx.x * 256 + 128 + t] = pq;
    }
}

// -------- stats reduce + BN params in one kernel (block = feature) ----------
__global__ __launch_bounds__(256) void k_stats_bn(const float* __restrict__ partial,
                                                  const float* __restrict__ g,
                                                  const float* __restrict__ beta,
                                                  float* __restrict__ prm,
                                                  int nblk, int n) {
    __shared__ float wsm[4], wqm[4];
    const int f = blockIdx.x;            // 0..127
    const int t = threadIdx.x;
    const int per = nblk / 256;          // 8
    float s = 0.f, q = 0.f;
    for (int i = 0; i < per; i++) {
        int p = t * per + i;
        s += partial[(size_t)p * 256 + f];
        q += partial[(size_t)p * 256 + 128 + f];
    }
#pragma unroll
    for (int off = 1; off < 64; off <<= 1) {
        s += __shfl_xor(s, off);
        q += __shfl_xor(q, off);
    }
    if ((t & 63) == 0) { wsm[t >> 6] = s; wqm[t >> 6] = q; }
    __syncthreads();
    if (t == 0) {
        float S = wsm[0] + wsm[1] + wsm[2] + wsm[3];
        float Q = wqm[0] + wqm[1] + wqm[2] + wqm[3];
        float inv_n = 1.0f / (float)n;
        float mu = S * inv_n;
        float var = Q * inv_n - mu * mu;
        float sc = rsqrtf(var + BN_EPS) * g[f];
        prm[f] = sc;
        prm[128 + f] = beta[f] - mu * sc;
    }
}

// ---------------- final BN apply + ReLU (bf16 agg -> f32 out) ----------------
__global__ __launch_bounds__(256) void k_bn_relu(const short* __restrict__ xbf,
                                                 float* __restrict__ y,
                                                 const float* __restrict__ prm, int n) {
    int idx = blockIdx.x * blockDim.x + threadIdx.x;
    const int total = n * 16;
    for (; idx < total; idx += gridDim.x * blockDim.x) {
        int node = idx >> 4;
        int f8 = (idx & 15) * 8;
        const uint4 v = *reinterpret_cast<const uint4*>(xbf + (size_t)node * 128 + f8);
        const float4 sc0 = *reinterpret_cast<const float4*>(prm + f8);
        const float4 sc1 = *reinterpret_cast<const float4*>(prm + f8 + 4);
        const float4 sh0 = *reinterpret_cast<const float4*>(prm + 128 + f8);
        const float4 sh1 = *reinterpret_cast<const float4*>(prm + 128 + f8 + 4);
        float4 o0, o1;
        o0.x = fmaxf(bflo(v.x) * sc0.x + sh0.x, 0.f);
        o0.y = fmaxf(bfhi(v.x) * sc0.y + sh0.y, 0.f);
        o0.z = fmaxf(bflo(v.y) * sc0.z + sh0.z, 0.f);
        o0.w = fmaxf(bfhi(v.y) * sc0.w + sh0.w, 0.f);
        o1.x = fmaxf(bflo(v.z) * sc1.x + sh1.x, 0.f);
        o1.y = fmaxf(bfhi(v.z) * sc1.y + sh1.y, 0.f);
        o1.z = fmaxf(bflo(v.w) * sc1.z + sh1.z, 0.f);
        o1.w = fmaxf(bfhi(v.w) * sc1.w + sh1.w, 0.f);
        float* yp = y + (size_t)node * 128 + f8;
        *reinterpret_cast<float4*>(yp) = o0;
        *reinterpret_cast<float4*>(yp + 4) = o1;
    }
}

extern "C" void kernel_launch(void* const* d_in, const int* in_sizes, int n_in,
                              void* d_out, int out_size, void* d_ws, size_t ws_size,
                              hipStream_t stream) {
    const float* x   = (const float*)d_in[0];
    const int*   ei  = (const int*)d_in[1];
    const float* ew  = (const float*)d_in[2];
    const float* W0  = (const float*)d_in[3];
    const float* b0  = (const float*)d_in[4];
    const float* g0  = (const float*)d_in[5];
    const float* be0 = (const float*)d_in[6];
    const float* W1  = (const float*)d_in[7];
    const float* b1  = (const float*)d_in[8];
    const float* g1  = (const float*)d_in[9];
    const float* be1 = (const float*)d_in[10];
    float* out = (float*)d_out;

    const int N = in_sizes[0] / FIN;          // 100000
    const int E = in_sizes[2];                // 1600000
    const int NBUK = (N + 127) >> 7;          // 782
    const int HB = 1024;                      // fine-grained hist blocks
    const int CHUNKH = (E + HB - 1) / HB;     // 1563
    const int CBC = 256;                      // phaseC blocks
    const int SUB = HB / CBC;                 // 4
    const int CHUNKC = CHUNKH * SUB;          // 6252
    const int GB = 2048;                      // gather grid

    // workspace layout
    short* aggbf    = (short*)d_ws;                          // [N,128] bf16
    short* hbf      = aggbf + (size_t)N * 128;               // [N,128] bf16
    int2*  recs     = (int2*)(hbf + (size_t)N * 128);        // [E]
    int2*  recs_mid = recs + E;                              // [E]
    unsigned* bcnt  = (unsigned*)(recs_mid + E);             // [HB*NBUK]
    unsigned* btotal= bcnt + (size_t)HB * NBUK;              // [NBUK]
    unsigned* bbase = btotal + NBUK;                         // [NBUK+1]
    float* dinv     = (float*)(bbase + NBUK + 1);            // [N]
    int*   rowptr   = (int*)(dinv + N);                      // [N+1]
    unsigned* ctr   = (unsigned*)(rowptr + N + 1);           // [2]
    float* prm      = (float*)(ctr + 2);                     // 256
    float* partial  = prm + 256;                             // [GB*256]

    // Wt staged in d_out (scratch until final bn_relu overwrites)
    short* Wt0 = (short*)d_out;            // [128][256] bf16
    short* Wt1 = Wt0 + 256 * 128;          // [128][128] bf16

    const int gemm_blocks = (N + 31) / 32;

    // ---- hist + weight prep ----
    hipMemsetAsync(ctr, 0, 8, stream);
    k_histprep<<<HB + 192, 256, 0, stream>>>(ei, E, HB, CHUNKH, NBUK, bcnt,
                                             W0, W1, Wt0, Wt1);
    k_phaseB<<<NBUK, 256, 0, stream>>>(bcnt, btotal, HB, NBUK);
    k_bsum<<<1, 256, 0, stream>>>(btotal, bbase, NBUK, E);

    // ---- fused bucket-scatter || gemm0 ----
    k_phaseCG<<<CBC + gemm_blocks, 256, 0, stream>>>(ei, ew, E, CHUNKC, NBUK, SUB,
                                                     bcnt, bbase, recs_mid, CBC,
                                                     x, Wt0, hbf, N);
    k_phaseD<<<NBUK, 256, 0, stream>>>(recs_mid, bbase, dinv, rowptr, recs, N, E);

    // ---- layer 0 ----
    k_gather_stats<<<GB, 256, 0, stream>>>(hbf, aggbf, rowptr, recs, dinv, b0,
                                           partial, ctr, N);
    k_stats_bn<<<128, 256, 0, stream>>>(partial, g0, be0, prm, GB, N);

    // ---- layer 1 ----
    k_gemm1<<<gemm_blocks, 256, 0, stream>>>(aggbf, Wt1, prm, hbf, N);
    k_gather_stats<<<GB, 256, 0, stream>>>(hbf, aggbf, rowptr, recs, dinv, b1,
                                           partial, ctr + 1, N);
    k_stats_bn<<<128, 256, 0, stream>>>(partial, g1, be1, prm, GB, N);
    k_bn_relu<<<2048, 256, 0, stream>>>(aggbf, out, prm, N);
}

// Round 16
// 459.113 us; speedup vs baseline: 2.0362x; 2.0362x over previous
//
#include <hip/hip_runtime.h>
#include <stdint.h>

#define FIN 256
#define FHID 128
#define BN_EPS 1e-3f

#ifndef USE_GLL
#if defined(__has_builtin)
#if __has_builtin(__builtin_amdgcn_global_load_lds)
#define USE_GLL 1
#else
#define USE_GLL 0
#endif
#else
#define USE_GLL 0
#endif
#endif

typedef short bf16x8 __attribute__((ext_vector_type(8)));
typedef float f32x4 __attribute__((ext_vector_type(4)));

__device__ inline short f2bf(float f) {
    unsigned u = __float_as_uint(f);
    unsigned r = (u + 0x7FFFu + ((u >> 16) & 1u)) >> 16;   // RNE
    return (short)r;
}
__device__ inline float bflo(unsigned v) { return __uint_as_float(v << 16); }
__device__ inline float bfhi(unsigned v) { return __uint_as_float(v & 0xFFFF0000u); }
__device__ inline float bf2f(short s) {
    return __uint_as_float(((unsigned)(unsigned short)s) << 16);
}

#define DEG_SCALE 131072.0f          // 2^17 fixed point
#define DEG_INV   (1.0f / 131072.0f)

// ------- hist (HB fine-grained blocks) || W0,W1 -> bf16 transposed ----------
__global__ __launch_bounds__(256) void k_histprep(const int* __restrict__ ei, int E,
                                                  int HB, int CHUNKH, int nbuk,
                                                  unsigned* __restrict__ bcnt,
                                                  const float* __restrict__ W0,
                                                  const float* __restrict__ W1,
                                                  short* __restrict__ Wt0,
                                                  short* __restrict__ Wt1) {
    __shared__ unsigned hist[1024];
    if ((int)blockIdx.x < HB) {
        for (int i = threadIdx.x; i < nbuk; i += 256) hist[i] = 0;
        __syncthreads();
        const int e0 = blockIdx.x * CHUNKH;
        const int e1 = min(e0 + CHUNKH, E);
        for (int e = e0 + threadIdx.x; e < e1; e += 256)
            atomicAdd(&hist[ei[E + e] >> 7], 1u);
        __syncthreads();
        for (int k = threadIdx.x; k < nbuk; k += 256)
            bcnt[(size_t)blockIdx.x * nbuk + k] = hist[k];
    } else {
        int idx = ((int)blockIdx.x - HB) * 256 + threadIdx.x;
        if (idx < 32768) {            // W0: [256][128] -> Wt0 [128][256]
            int n = idx >> 8, k = idx & 255;
            Wt0[idx] = f2bf(W0[k * 128 + n]);
        } else {
            int j = idx - 32768;      // W1: [128][128] -> Wt1 [128][128]
            if (j < 16384) {
                int n = j >> 7, k = j & 127;
                Wt1[j] = f2bf(W1[k * 128 + n]);
            }
        }
    }
}

// ---------------- gemm0 compute body (LDS-staged, swizzled) ----------------
__device__ __forceinline__ void gemm0_body(int bid, float* xs,
                                           const float* __restrict__ X,
                                           const short* __restrict__ Wt,
                                           short* __restrict__ H, int nrows) {
    const int t = threadIdx.x;
    const int lane = t & 63;
    const int w = t >> 6;
    const int r0 = bid * 32;
    const int l15 = lane & 15;
    const int q = lane >> 4;

#pragma unroll
    for (int i = 0; i < 8; i++) {
        const int row = w * 8 + i;
        int grow = r0 + row; if (grow >= nrows) grow = nrows - 1;
        const char* gsrc = (const char*)(X + (size_t)grow * 256);
        const int swz = (row & 7) << 4;
#if USE_GLL
        __builtin_amdgcn_global_load_lds(gsrc + ((lane * 16) ^ swz),
                                         xs + row * 256, 16, 0, 0);
#else
        const float4 v = *reinterpret_cast<const float4*>(gsrc + ((lane * 16) ^ swz));
        *reinterpret_cast<float4*>((char*)xs + row * 1024 + lane * 16) = v;
#endif
    }
    __syncthreads();

    const int n0 = w * 32;
    const int swzr = (l15 & 7) << 4;

    f32x4 acc[2][2];
#pragma unroll
    for (int mf = 0; mf < 2; mf++)
#pragma unroll
        for (int nf = 0; nf < 2; nf++)
#pragma unroll
            for (int r = 0; r < 4; r++) acc[mf][nf][r] = 0.0f;

#pragma unroll
    for (int ks = 0; ks < 8; ks++) {
        const int cb = ks * 128 + q * 32;
        bf16x8 a[2];
#pragma unroll
        for (int mf = 0; mf < 2; mf++) {
            const char* rb = (const char*)xs + (size_t)(mf * 16 + l15) * 1024;
            const float4 u0 = *reinterpret_cast<const float4*>(rb + (cb ^ swzr));
            const float4 u1 = *reinterpret_cast<const float4*>(rb + ((cb + 16) ^ swzr));
            bf16x8 tt;
            tt[0] = f2bf(u0.x); tt[1] = f2bf(u0.y); tt[2] = f2bf(u0.z); tt[3] = f2bf(u0.w);
            tt[4] = f2bf(u1.x); tt[5] = f2bf(u1.y); tt[6] = f2bf(u1.z); tt[7] = f2bf(u1.w);
            a[mf] = tt;
        }
        const bf16x8 b0 = *reinterpret_cast<const bf16x8*>(
            Wt + (size_t)(n0 + l15) * 256 + ks * 32 + q * 8);
        const bf16x8 b1 = *reinterpret_cast<const bf16x8*>(
            Wt + (size_t)(n0 + 16 + l15) * 256 + ks * 32 + q * 8);
        acc[0][0] = __builtin_amdgcn_mfma_f32_16x16x32_bf16(a[0], b0, acc[0][0], 0, 0, 0);
        acc[1][0] = __builtin_amdgcn_mfma_f32_16x16x32_bf16(a[1], b0, acc[1][0], 0, 0, 0);
        acc[0][1] = __builtin_amdgcn_mfma_f32_16x16x32_bf16(a[0], b1, acc[0][1], 0, 0, 0);
        acc[1][1] = __builtin_amdgcn_mfma_f32_16x16x32_bf16(a[1], b1, acc[1][1], 0, 0, 0);
    }

#pragma unroll
    for (int mf = 0; mf < 2; mf++) {
        const int rbase = r0 + mf * 16 + (lane >> 4) * 4;
#pragma unroll
        for (int r = 0; r < 4; r++) {
            const int row = rbase + r;
            if (row < nrows) {
#pragma unroll
                for (int nf = 0; nf < 2; nf++)
                    H[(size_t)row * 128 + n0 + nf * 16 + l15] = f2bf(acc[mf][nf][r]);
            }
        }
    }
}

// ------ fused: phaseC bucket-scatter (blocks < CBC)  ||  gemm0 (rest) -------
__global__ __launch_bounds__(256) void k_phaseCG(const int* __restrict__ ei,
                                                 const float* __restrict__ ew,
                                                 int E, int CHUNKC, int nbuk, int sub,
                                                 const unsigned* __restrict__ bcnt,
                                                 const unsigned* __restrict__ bbase,
                                                 int2* __restrict__ recs_mid,
                                                 int CBC,
                                                 const float* __restrict__ X,
                                                 const short* __restrict__ Wt,
                                                 short* __restrict__ H, int nrows) {
    __shared__ float xs[8192];   // 32KB; phaseC aliases first 4KB as cursors
    if ((int)blockIdx.x < CBC) {
        unsigned* curs = (unsigned*)xs;
        const int b = blockIdx.x;
        for (int k = threadIdx.x; k < nbuk; k += 256)
            curs[k] = bbase[k] + bcnt[(size_t)(b * sub) * nbuk + k];
        __syncthreads();
        const int e0 = b * CHUNKC;
        const int e1 = min(e0 + CHUNKC, E);
        for (int base = e0; base < e1; base += 1024) {
            const int e = base + threadIdx.x * 4;
            if (e + 3 < e1) {
                const int4 s4 = *reinterpret_cast<const int4*>(ei + e);
                const int4 d4 = *reinterpret_cast<const int4*>(ei + E + e);
                const float4 w4 = *reinterpret_cast<const float4*>(ew + e);
                unsigned p0 = atomicAdd(&curs[d4.x >> 7], 1u);
                recs_mid[p0] = make_int2(s4.x | ((d4.x & 127) << 17), __float_as_int(w4.x));
                unsigned p1 = atomicAdd(&curs[d4.y >> 7], 1u);
                recs_mid[p1] = make_int2(s4.y | ((d4.y & 127) << 17), __float_as_int(w4.y));
                unsigned p2 = atomicAdd(&curs[d4.z >> 7], 1u);
                recs_mid[p2] = make_int2(s4.z | ((d4.z & 127) << 17), __float_as_int(w4.z));
                unsigned p3 = atomicAdd(&curs[d4.w >> 7], 1u);
                recs_mid[p3] = make_int2(s4.w | ((d4.w & 127) << 17), __float_as_int(w4.w));
            } else {
#pragma unroll
                for (int j = 0; j < 4; j++) {
                    const int ee = e + j;
                    if (ee < e1) {
                        int src = ei[ee];
                        int dst = ei[E + ee];
                        unsigned pos = atomicAdd(&curs[dst >> 7], 1u);
                        recs_mid[pos] = make_int2(src | ((dst & 127) << 17),
                                                  __float_as_int(ew[ee]));
                    }
                }
            }
        }
    } else {
        gemm0_body((int)blockIdx.x - CBC, xs, X, Wt, H, nrows);
    }
}

// ---------------- GEMM1: bf16 agg staged to LDS + BN0+ReLU fused ------------
__global__ __launch_bounds__(256) void k_gemm1(const short* __restrict__ X,
                                               const short* __restrict__ Wt,
                                               const float* __restrict__ prm,
                                               short* __restrict__ H, int nrows) {
    __shared__ short xs[4096];   // 8KB
    const int t = threadIdx.x;
    const int lane = t & 63;
    const int w = t >> 6;
    const int r0 = blockIdx.x * 32;
    const int l15 = lane & 15;
    const int q = lane >> 4;

#pragma unroll
    for (int j = 0; j < 2; j++) {
        const int rbase = w * 8 + j * 4;
        const int row = rbase + q;
        int grow = r0 + row; if (grow >= nrows) grow = nrows - 1;
        const char* gsrc = (const char*)(X + (size_t)grow * 128);
        const int swz = (row & 7) << 4;
#if USE_GLL
        __builtin_amdgcn_global_load_lds(gsrc + (((lane & 15) * 16) ^ swz),
                                         xs + rbase * 128, 16, 0, 0);
#else
        const uint4 v = *reinterpret_cast<const uint4*>(gsrc + (((lane & 15) * 16) ^ swz));
        *reinterpret_cast<uint4*>((char*)xs + rbase * 256 + lane * 16) = v;
#endif
    }
    __syncthreads();

    const int n0 = w * 32;
    const int swzr = (l15 & 7) << 4;

    f32x4 acc[2][2];
#pragma unroll
    for (int mf = 0; mf < 2; mf++)
#pragma unroll
        for (int nf = 0; nf < 2; nf++)
#pragma unroll
            for (int r = 0; r < 4; r++) acc[mf][nf][r] = 0.0f;

#pragma unroll
    for (int ks = 0; ks < 4; ks++) {
        const int kb = ks * 32 + q * 8;
        const int cb = ks * 64 + q * 16;
        const float4 sc0 = *reinterpret_cast<const float4*>(prm + kb);
        const float4 sc1 = *reinterpret_cast<const float4*>(prm + kb + 4);
        const float4 sh0 = *reinterpret_cast<const float4*>(prm + 128 + kb);
        const float4 sh1 = *reinterpret_cast<const float4*>(prm + 128 + kb + 4);
        bf16x8 a[2];
#pragma unroll
        for (int mf = 0; mf < 2; mf++) {
            const char* rb = (const char*)xs + (size_t)(mf * 16 + l15) * 256;
            const bf16x8 ar = *reinterpret_cast<const bf16x8*>(rb + (cb ^ swzr));
            bf16x8 tt;
            tt[0] = f2bf(fmaxf(bf2f(ar[0]) * sc0.x + sh0.x, 0.f));
            tt[1] = f2bf(fmaxf(bf2f(ar[1]) * sc0.y + sh0.y, 0.f));
            tt[2] = f2bf(fmaxf(bf2f(ar[2]) * sc0.z + sh0.z, 0.f));
            tt[3] = f2bf(fmaxf(bf2f(ar[3]) * sc0.w + sh0.w, 0.f));
            tt[4] = f2bf(fmaxf(bf2f(ar[4]) * sc1.x + sh1.x, 0.f));
            tt[5] = f2bf(fmaxf(bf2f(ar[5]) * sc1.y + sh1.y, 0.f));
            tt[6] = f2bf(fmaxf(bf2f(ar[6]) * sc1.z + sh1.z, 0.f));
            tt[7] = f2bf(fmaxf(bf2f(ar[7]) * sc1.w + sh1.w, 0.f));
            a[mf] = tt;
        }
        const bf16x8 b0 = *reinterpret_cast<const bf16x8*>(
            Wt + (size_t)(n0 + l15) * 128 + kb);
        const bf16x8 b1 = *reinterpret_cast<const bf16x8*>(
            Wt + (size_t)(n0 + 16 + l15) * 128 + kb);
        acc[0][0] = __builtin_amdgcn_mfma_f32_16x16x32_bf16(a[0], b0, acc[0][0], 0, 0, 0);
        acc[1][0] = __builtin_amdgcn_mfma_f32_16x16x32_bf16(a[1], b0, acc[1][0], 0, 0, 0);
        acc[0][1] = __builtin_amdgcn_mfma_f32_16x16x32_bf16(a[0], b1, acc[0][1], 0, 0, 0);
        acc[1][1] = __builtin_amdgcn_mfma_f32_16x16x32_bf16(a[1], b1, acc[1][1], 0, 0, 0);
    }

#pragma unroll
    for (int mf = 0; mf < 2; mf++) {
        const int rbase = r0 + mf * 16 + (lane >> 4) * 4;
#pragma unroll
        for (int r = 0; r < 4; r++) {
            const int row = rbase + r;
            if (row < nrows) {
#pragma unroll
                for (int nf = 0; nf < 2; nf++)
                    H[(size_t)row * 128 + n0 + nf * 16 + l15] = f2bf(acc[mf][nf][r]);
            }
        }
    }
}

// -------- phase B: per-bucket scan of HB block counts (4/thread) ------------
__global__ __launch_bounds__(256) void k_phaseB(unsigned* __restrict__ bcnt,
                                                unsigned* __restrict__ btotal,
                                                int HB, int nbuk) {
    __shared__ unsigned lds[256];
    const int k = blockIdx.x;
    const int t = threadIdx.x;
    unsigned v[4];
    unsigned s = 0;
#pragma unroll
    for (int i = 0; i < 4; i++) {
        int j = t * 4 + i;
        v[i] = (j < HB) ? bcnt[(size_t)j * nbuk + k] : 0;
        s += v[i];
    }
    lds[t] = s;
    __syncthreads();
    for (int off = 1; off < 256; off <<= 1) {
        unsigned add = (t >= off) ? lds[t - off] : 0;
        __syncthreads();
        lds[t] += add;
        __syncthreads();
    }
    unsigned run = lds[t] - s;
#pragma unroll
    for (int i = 0; i < 4; i++) {
        int j = t * 4 + i;
        if (j < HB) bcnt[(size_t)j * nbuk + k] = run;
        run += v[i];
    }
    if (t == 255) btotal[k] = lds[255];
}

// ---------------- bucket base scan (single block) ----------------
__global__ __launch_bounds__(256) void k_bsum(const unsigned* __restrict__ btotal,
                                              unsigned* __restrict__ bbase,
                                              int nbuk, int E) {
    __shared__ unsigned lds[256];
    const int t = threadIdx.x;
    unsigned v[4];
    unsigned s = 0;
#pragma unroll
    for (int i = 0; i < 4; i++) {
        int j = t * 4 + i;
        v[i] = (j < nbuk) ? btotal[j] : 0;
        s += v[i];
    }
    lds[t] = s;
    __syncthreads();
    for (int off = 1; off < 256; off <<= 1) {
        unsigned add = (t >= off) ? lds[t - off] : 0;
        __syncthreads();
        lds[t] += add;
        __syncthreads();
    }
    unsigned run = lds[t] - s;
#pragma unroll
    for (int i = 0; i < 4; i++) {
        int j = t * 4 + i;
        if (j < nbuk) bbase[j] = run;
        run += v[i];
    }
    if (t == 255) bbase[nbuk] = (unsigned)E;
}

// ---- phase D: per-bucket dst sort, dinv, rowptr, recs (ew*dinv_dst) --------
__global__ __launch_bounds__(256) void k_phaseD(const int2* __restrict__ recs_mid,
                                                const unsigned* __restrict__ bbase,
                                                float* __restrict__ dinv,
                                                int* __restrict__ rowptr,
                                                int2* __restrict__ recs,
                                                int n, int E) {
    __shared__ unsigned cnt[128], wsum[128], rank[128], sc[128], base[128];
    __shared__ float dloc[128];
    const int k = blockIdx.x;
    const int t = threadIdx.x;
    if (t < 128) { cnt[t] = 0; wsum[t] = 0; rank[t] = 0; }
    __syncthreads();
    const unsigned s0 = bbase[k], s1 = bbase[k + 1];
    for (unsigned i = s0 + t; i < s1; i += 256) {
        int2 r = recs_mid[i];
        int dl = (r.x >> 17) & 127;
        atomicAdd(&cnt[dl], 1u);
        atomicAdd(&wsum[dl], (unsigned)(__int_as_float(r.y) * DEG_SCALE));
    }
    __syncthreads();
    if (t < 128) sc[t] = cnt[t];
    __syncthreads();
    for (int off = 1; off < 128; off <<= 1) {
        unsigned add = (t < 128 && t >= off) ? sc[t - off] : 0;
        __syncthreads();
        if (t < 128) sc[t] += add;
        __syncthreads();
    }
    if (t < 128) {
        unsigned excl = sc[t] - cnt[t];
        base[t] = s0 + excl;
        int dst = k * 128 + t;
        if (dst < n) {
            float dg = (float)wsum[t] * DEG_INV + 1.0f;
            float dv = rsqrtf(dg);
            dloc[t] = dv;
            dinv[dst] = dv;
            rowptr[dst] = (int)(s0 + excl);
        }
    }
    if (k == 0 && t == 0) rowptr[n] = E;
    __syncthreads();
    for (unsigned i = s0 + t; i < s1; i += 256) {
        int2 r = recs_mid[i];
        int dl = (r.x >> 17) & 127;
        unsigned rr = atomicAdd(&rank[dl], 1u);
        float w2 = __int_as_float(r.y) * dloc[dl];     // ew * dinv[dst]
        recs[base[dl] + rr] = make_int2(r.x & 0x1FFFF, __float_as_int(w2));
    }
}

// --- gather + stats: 32-sharded wave-dynamic 8-node chunks (no barriers) ----
__global__ __launch_bounds__(256) void k_gather_stats(const short* __restrict__ h,
                                                      short* __restrict__ aggbf,
                                                      const int* __restrict__ rowptr,
                                                      const int2* __restrict__ recs,
                                                      const float* __restrict__ dinv,
                                                      const float* __restrict__ bias,
                                                      float* __restrict__ partial,
                                                      unsigned* __restrict__ ctr,
                                                      int n, int shardN) {
    __shared__ float lsum[4][128], lsq[4][128];
    const int w = threadIdx.x >> 6;
    const int lane = threadIdx.x & 63;
    const int q3 = lane >> 4;            // quarter id
    const int f8 = (lane & 15) * 8;      // feature slice [f8, f8+8)
    const int shard = blockIdx.x & 31;
    const int sbase = shard * shardN;
    const int send = min(sbase + shardN, n);
    const float4 bv0 = *reinterpret_cast<const float4*>(bias + f8);
    const float4 bv1 = *reinterpret_cast<const float4*>(bias + f8 + 4);
    float s[8], qq[8];
#pragma unroll
    for (int j = 0; j < 8; j++) { s[j] = 0.f; qq[j] = 0.f; }

    for (;;) {
        int off = 0;
        if (lane == 0) off = (int)atomicAdd(&ctr[shard], 8u);
        off = __shfl(off, 0);
        const int nb = sbase + off;
        if (nb >= send) break;
#pragma unroll
        for (int rr2 = 0; rr2 < 2; rr2++) {
            const int node = nb + rr2 * 4 + q3;
            if (node < send) {
                float a[8];
#pragma unroll
                for (int j = 0; j < 8; j++) a[j] = 0.f;
                int e = rowptr[node];
                const int end = rowptr[node + 1];
                for (; e + 4 <= end; e += 4) {
                    const int2 r0 = recs[e];
                    const int2 r1 = recs[e + 1];
                    const int2 r2 = recs[e + 2];
                    const int2 r3 = recs[e + 3];
                    const float d0 = dinv[r0.x];
                    const float d1 = dinv[r1.x];
                    const float d2 = dinv[r2.x];
                    const float d3 = dinv[r3.x];
                    const uint4 v0 = *reinterpret_cast<const uint4*>(h + (size_t)r0.x * 128 + f8);
                    const uint4 v1 = *reinterpret_cast<const uint4*>(h + (size_t)r1.x * 128 + f8);
                    const uint4 v2 = *reinterpret_cast<const uint4*>(h + (size_t)r2.x * 128 + f8);
                    const uint4 v3 = *reinterpret_cast<const uint4*>(h + (size_t)r3.x * 128 + f8);
                    const float w0 = __int_as_float(r0.y) * d0;
                    const float w1 = __int_as_float(r1.y) * d1;
                    const float w2 = __int_as_float(r2.y) * d2;
                    const float w3 = __int_as_float(r3.y) * d3;
                    a[0] += bflo(v0.x) * w0; a[1] += bfhi(v0.x) * w0;
                    a[2] += bflo(v0.y) * w0; a[3] += bfhi(v0.y) * w0;
                    a[4] += bflo(v0.z) * w0; a[5] += bfhi(v0.z) * w0;
                    a[6] += bflo(v0.w) * w0; a[7] += bfhi(v0.w) * w0;
                    a[0] += bflo(v1.x) * w1; a[1] += bfhi(v1.x) * w1;
                    a[2] += bflo(v1.y) * w1; a[3] += bfhi(v1.y) * w1;
                    a[4] += bflo(v1.z) * w1; a[5] += bfhi(v1.z) * w1;
                    a[6] += bflo(v1.w) * w1; a[7] += bfhi(v1.w) * w1;
                    a[0] += bflo(v2.x) * w2; a[1] += bfhi(v2.x) * w2;
                    a[2] += bflo(v2.y) * w2; a[3] += bfhi(v2.y) * w2;
                    a[4] += bflo(v2.z) * w2; a[5] += bfhi(v2.z) * w2;
                    a[6] += bflo(v2.w) * w2; a[7] += bfhi(v2.w) * w2;
                    a[0] += bflo(v3.x) * w3; a[1] += bfhi(v3.x) * w3;
                    a[2] += bflo(v3.y) * w3; a[3] += bfhi(v3.y) * w3;
                    a[4] += bflo(v3.z) * w3; a[5] += bfhi(v3.z) * w3;
                    a[6] += bflo(v3.w) * w3; a[7] += bfhi(v3.w) * w3;
                }
                for (; e < end; e++) {
                    const int2 r = recs[e];
                    const float d = dinv[r.x];
                    const uint4 v = *reinterpret_cast<const uint4*>(h + (size_t)r.x * 128 + f8);
                    const float w0 = __int_as_float(r.y) * d;
                    a[0] += bflo(v.x) * w0; a[1] += bfhi(v.x) * w0;
                    a[2] += bflo(v.y) * w0; a[3] += bfhi(v.y) * w0;
                    a[4] += bflo(v.z) * w0; a[5] += bfhi(v.z) * w0;
                    a[6] += bflo(v.w) * w0; a[7] += bfhi(v.w) * w0;
                }
                const float di = dinv[node];
                const float sl = di * di;
                const uint4 hv = *reinterpret_cast<const uint4*>(h + (size_t)node * 128 + f8);
                float o[8];
                o[0] = a[0] + bflo(hv.x) * sl + bv0.x;
                o[1] = a[1] + bfhi(hv.x) * sl + bv0.y;
                o[2] = a[2] + bflo(hv.y) * sl + bv0.z;
                o[3] = a[3] + bfhi(hv.y) * sl + bv0.w;
                o[4] = a[4] + bflo(hv.z) * sl + bv1.x;
                o[5] = a[5] + bfhi(hv.z) * sl + bv1.y;
                o[6] = a[6] + bflo(hv.w) * sl + bv1.z;
                o[7] = a[7] + bfhi(hv.w) * sl + bv1.w;
                bf16x8 ob;
#pragma unroll
                for (int j = 0; j < 8; j++) ob[j] = f2bf(o[j]);
                *reinterpret_cast<bf16x8*>(aggbf + (size_t)node * 128 + f8) = ob;
#pragma unroll
                for (int j = 0; j < 8; j++) { s[j] += o[j]; qq[j] += o[j] * o[j]; }
            }
        }
    }

#pragma unroll
    for (int j = 0; j < 8; j++) {
        s[j] += __shfl_xor(s[j], 16);  s[j] += __shfl_xor(s[j], 32);
        qq[j] += __shfl_xor(qq[j], 16); qq[j] += __shfl_xor(qq[j], 32);
    }
    if (q3 == 0) {
        *reinterpret_cast<float4*>(&lsum[w][f8]) = make_float4(s[0], s[1], s[2], s[3]);
        *reinterpret_cast<float4*>(&lsum[w][f8 + 4]) = make_float4(s[4], s[5], s[6], s[7]);
        *reinterpret_cast<float4*>(&lsq[w][f8]) = make_float4(qq[0], qq[1], qq[2], qq[3]);
        *reinterpret_cast<float4*>(&lsq[w][f8 + 4]) = make_float4(qq[4], qq[5], qq[6], qq[7]);
    }
    __syncthreads();
    const int t = threadIdx.x;
    if (t < 128) {
        float ps = lsum[0][t] + lsum[1][t] + lsum[2][t] + lsum[3][t];
        float pq = lsq[0][t] + lsq[1][t] + lsq[2][t] + lsq[3][t];
        partial[(size_t)blockIdx.x * 256 + t] = ps;
        partial[(size_t)blockIdx.x * 256 + 128 + t] = pq;
    }
}

// -------- stats reduce + BN params in one kernel (block = feature) ----------
__global__ __launch_bounds__(256) void k_stats_bn(const float* __restrict__ partial,
                                                  const float* __restrict__ g,
                                                  const float* __restrict__ beta,
                                                  float* __restrict__ prm,
                                                  int nblk, int n) {
    __shared__ float wsm[4], wqm[4];
    const int f = blockIdx.x;            // 0..127
    const int t = threadIdx.x;
    const int per = nblk / 256;          // 8
    float s = 0.f, q = 0.f;
    for (int i = 0; i < per; i++) {
        int p = t * per + i;
        s += partial[(size_t)p * 256 + f];
        q += partial[(size_t)p * 256 + 128 + f];
    }
#pragma unroll
    for (int off = 1; off < 64; off <<= 1) {
        s += __shfl_xor(s, off);
        q += __shfl_xor(q, off);
    }
    if ((t & 63) == 0) { wsm[t >> 6] = s; wqm[t >> 6] = q; }
    __syncthreads();
    if (t == 0) {
        float S = wsm[0] + wsm[1] + wsm[2] + wsm[3];
        float Q = wqm[0] + wqm[1] + wqm[2] + wqm[3];
        float inv_n = 1.0f / (float)n;
        float mu = S * inv_n;
        float var = Q * inv_n - mu * mu;
        float sc = rsqrtf(var + BN_EPS) * g[f];
        prm[f] = sc;
        prm[128 + f] = beta[f] - mu * sc;
    }
}

// ---------------- final BN apply + ReLU (bf16 agg -> f32 out) ----------------
__global__ __launch_bounds__(256) void k_bn_relu(const short* __restrict__ xbf,
                                                 float* __restrict__ y,
                                                 const float* __restrict__ prm, int n) {
    int idx = blockIdx.x * blockDim.x + threadIdx.x;
    const int total = n * 16;
    for (; idx < total; idx += gridDim.x * blockDim.x) {
        int node = idx >> 4;
        int f8 = (idx & 15) * 8;
        const uint4 v = *reinterpret_cast<const uint4*>(xbf + (size_t)node * 128 + f8);
        const float4 sc0 = *reinterpret_cast<const float4*>(prm + f8);
        const float4 sc1 = *reinterpret_cast<const float4*>(prm + f8 + 4);
        const float4 sh0 = *reinterpret_cast<const float4*>(prm + 128 + f8);
        const float4 sh1 = *reinterpret_cast<const float4*>(prm + 128 + f8 + 4);
        float4 o0, o1;
        o0.x = fmaxf(bflo(v.x) * sc0.x + sh0.x, 0.f);
        o0.y = fmaxf(bfhi(v.x) * sc0.y + sh0.y, 0.f);
        o0.z = fmaxf(bflo(v.y) * sc0.z + sh0.z, 0.f);
        o0.w = fmaxf(bfhi(v.y) * sc0.w + sh0.w, 0.f);
        o1.x = fmaxf(bflo(v.z) * sc1.x + sh1.x, 0.f);
        o1.y = fmaxf(bfhi(v.z) * sc1.y + sh1.y, 0.f);
        o1.z = fmaxf(bflo(v.w) * sc1.z + sh1.z, 0.f);
        o1.w = fmaxf(bfhi(v.w) * sc1.w + sh1.w, 0.f);
        float* yp = y + (size_t)node * 128 + f8;
        *reinterpret_cast<float4*>(yp) = o0;
        *reinterpret_cast<float4*>(yp + 4) = o1;
    }
}

extern "C" void kernel_launch(void* const* d_in, const int* in_sizes, int n_in,
                              void* d_out, int out_size, void* d_ws, size_t ws_size,
                              hipStream_t stream) {
    const float* x   = (const float*)d_in[0];
    const int*   ei  = (const int*)d_in[1];
    const float* ew  = (const float*)d_in[2];
    const float* W0  = (const float*)d_in[3];
    const float* b0  = (const float*)d_in[4];
    const float* g0  = (const float*)d_in[5];
    const float* be0 = (const float*)d_in[6];
    const float* W1  = (const float*)d_in[7];
    const float* b1  = (const float*)d_in[8];
    const float* g1  = (const float*)d_in[9];
    const float* be1 = (const float*)d_in[10];
    float* out = (float*)d_out;

    const int N = in_sizes[0] / FIN;          // 100000
    const int E = in_sizes[2];                // 1600000
    const int NBUK = (N + 127) >> 7;          // 782
    const int HB = 1024;                      // fine-grained hist blocks
    const int CHUNKH = (E + HB - 1) / HB;     // 1563
    const int CBC = 256;                      // phaseC blocks
    const int SUB = HB / CBC;                 // 4
    const int CHUNKC = CHUNKH * SUB;          // 6252
    const int GB = 2048;                      // gather grid
    const int SHARDN = (N + 31) / 32;         // 3125 nodes per shard

    // workspace layout
    short* aggbf    = (short*)d_ws;                          // [N,128] bf16
    short* hbf      = aggbf + (size_t)N * 128;               // [N,128] bf16
    int2*  recs     = (int2*)(hbf + (size_t)N * 128);        // [E]
    int2*  recs_mid = recs + E;                              // [E]
    unsigned* bcnt  = (unsigned*)(recs_mid + E);             // [HB*NBUK]
    unsigned* btotal= bcnt + (size_t)HB * NBUK;              // [NBUK]
    unsigned* bbase = btotal + NBUK;                         // [NBUK+1]
    float* dinv     = (float*)(bbase + NBUK + 1);            // [N]
    int*   rowptr   = (int*)(dinv + N);                      // [N+1]
    unsigned* ctr   = (unsigned*)(rowptr + N + 1);           // [64] (32 per layer)
    float* prm      = (float*)(ctr + 64);                    // 256
    float* partial  = prm + 256;                             // [GB*256]

    // Wt staged in d_out (scratch until final bn_relu overwrites)
    short* Wt0 = (short*)d_out;            // [128][256] bf16
    short* Wt1 = Wt0 + 256 * 128;          // [128][128] bf16

    const int gemm_blocks = (N + 31) / 32;

    // ---- hist + weight prep ----
    hipMemsetAsync(ctr, 0, 64 * sizeof(unsigned), stream);
    k_histprep<<<HB + 192, 256, 0, stream>>>(ei, E, HB, CHUNKH, NBUK, bcnt,
                                             W0, W1, Wt0, Wt1);
    k_phaseB<<<NBUK, 256, 0, stream>>>(bcnt, btotal, HB, NBUK);
    k_bsum<<<1, 256, 0, stream>>>(btotal, bbase, NBUK, E);

    // ---- fused bucket-scatter || gemm0 ----
    k_phaseCG<<<CBC + gemm_blocks, 256, 0, stream>>>(ei, ew, E, CHUNKC, NBUK, SUB,
                                                     bcnt, bbase, recs_mid, CBC,
                                                     x, Wt0, hbf, N);
    k_phaseD<<<NBUK, 256, 0, stream>>>(recs_mid, bbase, dinv, rowptr, recs, N, E);

    // ---- layer 0 ----
    k_gather_stats<<<GB, 256, 0, stream>>>(hbf, aggbf, rowptr, recs, dinv, b0,
                                           partial, ctr, N, SHARDN);
    k_stats_bn<<<128, 256, 0, stream>>>(partial, g0, be0, prm, GB, N);

    // ---- layer 1 ----
    k_gemm1<<<gemm_blocks, 256, 0, stream>>>(aggbf, Wt1, prm, hbf, N);
    k_gather_stats<<<GB, 256, 0, stream>>>(hbf, aggbf, rowptr, recs, dinv, b1,
                                           partial, ctr + 32, N, SHARDN);
    k_stats_bn<<<128, 256, 0, stream>>>(partial, g1, be1, prm, GB, N);
    k_bn_relu<<<2048, 256, 0, stream>>>(aggbf, out, prm, N);
}

// Round 17
// 287.251 us; speedup vs baseline: 3.2544x; 1.5983x over previous
//
#include <hip/hip_runtime.h>
#include <stdint.h>

#define FIN 256
#define FHID 128
#define BN_EPS 1e-3f

#ifndef USE_GLL
#if defined(__has_builtin)
#if __has_builtin(__builtin_amdgcn_global_load_lds)
#define USE_GLL 1
#else
#define USE_GLL 0
#endif
#else
#define USE_GLL 0
#endif
#endif

typedef short bf16x8 __attribute__((ext_vector_type(8)));
typedef float f32x4 __attribute__((ext_vector_type(4)));

__device__ inline short f2bf(float f) {
    unsigned u = __float_as_uint(f);
    unsigned r = (u + 0x7FFFu + ((u >> 16) & 1u)) >> 16;   // RNE
    return (short)r;
}
__device__ inline float bflo(unsigned v) { return __uint_as_float(v << 16); }
__device__ inline float bfhi(unsigned v) { return __uint_as_float(v & 0xFFFF0000u); }
__device__ inline float bf2f(short s) {
    return __uint_as_float(((unsigned)(unsigned short)s) << 16);
}

#define DEG_SCALE 131072.0f          // 2^17 fixed point
#define DEG_INV   (1.0f / 131072.0f)

// ------- hist (HB fine-grained blocks) || W0,W1 -> bf16 transposed ----------
__global__ __launch_bounds__(256) void k_histprep(const int* __restrict__ ei, int E,
                                                  int HB, int CHUNKH, int nbuk,
                                                  unsigned* __restrict__ bcnt,
                                                  const float* __restrict__ W0,
                                                  const float* __restrict__ W1,
                                                  short* __restrict__ Wt0,
                                                  short* __restrict__ Wt1) {
    __shared__ unsigned hist[1024];
    if ((int)blockIdx.x < HB) {
        for (int i = threadIdx.x; i < nbuk; i += 256) hist[i] = 0;
        __syncthreads();
        const int e0 = blockIdx.x * CHUNKH;
        const int e1 = min(e0 + CHUNKH, E);
        for (int e = e0 + threadIdx.x; e < e1; e += 256)
            atomicAdd(&hist[ei[E + e] >> 7], 1u);
        __syncthreads();
        for (int k = threadIdx.x; k < nbuk; k += 256)
            bcnt[(size_t)blockIdx.x * nbuk + k] = hist[k];
    } else {
        int idx = ((int)blockIdx.x - HB) * 256 + threadIdx.x;
        if (idx < 32768) {            // W0: [256][128] -> Wt0 [128][256]
            int n = idx >> 8, k = idx & 255;
            Wt0[idx] = f2bf(W0[k * 128 + n]);
        } else {
            int j = idx - 32768;      // W1: [128][128] -> Wt1 [128][128]
            if (j < 16384) {
                int n = j >> 7, k = j & 127;
                Wt1[j] = f2bf(W1[k * 128 + n]);
            }
        }
    }
}

// ---------------- gemm0 compute body (LDS-staged, swizzled) ----------------
__device__ __forceinline__ void gemm0_body(int bid, float* xs,
                                           const float* __restrict__ X,
                                           const short* __restrict__ Wt,
                                           short* __restrict__ H, int nrows) {
    const int t = threadIdx.x;
    const int lane = t & 63;
    const int w = t >> 6;
    const int r0 = bid * 32;
    const int l15 = lane & 15;
    const int q = lane >> 4;

#pragma unroll
    for (int i = 0; i < 8; i++) {
        const int row = w * 8 + i;
        int grow = r0 + row; if (grow >= nrows) grow = nrows - 1;
        const char* gsrc = (const char*)(X + (size_t)grow * 256);
        const int swz = (row & 7) << 4;
#if USE_GLL
        __builtin_amdgcn_global_load_lds(gsrc + ((lane * 16) ^ swz),
                                         xs + row * 256, 16, 0, 0);
#else
        const float4 v = *reinterpret_cast<const float4*>(gsrc + ((lane * 16) ^ swz));
        *reinterpret_cast<float4*>((char*)xs + row * 1024 + lane * 16) = v;
#endif
    }
    __syncthreads();

    const int n0 = w * 32;
    const int swzr = (l15 & 7) << 4;

    f32x4 acc[2][2];
#pragma unroll
    for (int mf = 0; mf < 2; mf++)
#pragma unroll
        for (int nf = 0; nf < 2; nf++)
#pragma unroll
            for (int r = 0; r < 4; r++) acc[mf][nf][r] = 0.0f;

#pragma unroll
    for (int ks = 0; ks < 8; ks++) {
        const int cb = ks * 128 + q * 32;
        bf16x8 a[2];
#pragma unroll
        for (int mf = 0; mf < 2; mf++) {
            const char* rb = (const char*)xs + (size_t)(mf * 16 + l15) * 1024;
            const float4 u0 = *reinterpret_cast<const float4*>(rb + (cb ^ swzr));
            const float4 u1 = *reinterpret_cast<const float4*>(rb + ((cb + 16) ^ swzr));
            bf16x8 tt;
            tt[0] = f2bf(u0.x); tt[1] = f2bf(u0.y); tt[2] = f2bf(u0.z); tt[3] = f2bf(u0.w);
            tt[4] = f2bf(u1.x); tt[5] = f2bf(u1.y); tt[6] = f2bf(u1.z); tt[7] = f2bf(u1.w);
            a[mf] = tt;
        }
        const bf16x8 b0 = *reinterpret_cast<const bf16x8*>(
            Wt + (size_t)(n0 + l15) * 256 + ks * 32 + q * 8);
        const bf16x8 b1 = *reinterpret_cast<const bf16x8*>(
            Wt + (size_t)(n0 + 16 + l15) * 256 + ks * 32 + q * 8);
        acc[0][0] = __builtin_amdgcn_mfma_f32_16x16x32_bf16(a[0], b0, acc[0][0], 0, 0, 0);
        acc[1][0] = __builtin_amdgcn_mfma_f32_16x16x32_bf16(a[1], b0, acc[1][0], 0, 0, 0);
        acc[0][1] = __builtin_amdgcn_mfma_f32_16x16x32_bf16(a[0], b1, acc[0][1], 0, 0, 0);
        acc[1][1] = __builtin_amdgcn_mfma_f32_16x16x32_bf16(a[1], b1, acc[1][1], 0, 0, 0);
    }

#pragma unroll
    for (int mf = 0; mf < 2; mf++) {
        const int rbase = r0 + mf * 16 + (lane >> 4) * 4;
#pragma unroll
        for (int r = 0; r < 4; r++) {
            const int row = rbase + r;
            if (row < nrows) {
#pragma unroll
                for (int nf = 0; nf < 2; nf++)
                    H[(size_t)row * 128 + n0 + nf * 16 + l15] = f2bf(acc[mf][nf][r]);
            }
        }
    }
}

// ------ fused: phaseC bucket-scatter (blocks < CBC)  ||  gemm0 (rest) -------
__global__ __launch_bounds__(256) void k_phaseCG(const int* __restrict__ ei,
                                                 const float* __restrict__ ew,
                                                 int E, int CHUNKC, int nbuk, int sub,
                                                 const unsigned* __restrict__ bcnt,
                                                 const unsigned* __restrict__ bbase,
                                                 int2* __restrict__ recs_mid,
                                                 int CBC,
                                                 const float* __restrict__ X,
                                                 const short* __restrict__ Wt,
                                                 short* __restrict__ H, int nrows) {
    __shared__ float xs[8192];   // 32KB; phaseC aliases first 4KB as cursors
    if ((int)blockIdx.x < CBC) {
        unsigned* curs = (unsigned*)xs;
        const int b = blockIdx.x;
        for (int k = threadIdx.x; k < nbuk; k += 256)
            curs[k] = bbase[k] + bcnt[(size_t)(b * sub) * nbuk + k];
        __syncthreads();
        const int e0 = b * CHUNKC;
        const int e1 = min(e0 + CHUNKC, E);
        for (int base = e0; base < e1; base += 1024) {
            const int e = base + threadIdx.x * 4;
            if (e + 3 < e1) {
                const int4 s4 = *reinterpret_cast<const int4*>(ei + e);
                const int4 d4 = *reinterpret_cast<const int4*>(ei + E + e);
                const float4 w4 = *reinterpret_cast<const float4*>(ew + e);
                unsigned p0 = atomicAdd(&curs[d4.x >> 7], 1u);
                recs_mid[p0] = make_int2(s4.x | ((d4.x & 127) << 17), __float_as_int(w4.x));
                unsigned p1 = atomicAdd(&curs[d4.y >> 7], 1u);
                recs_mid[p1] = make_int2(s4.y | ((d4.y & 127) << 17), __float_as_int(w4.y));
                unsigned p2 = atomicAdd(&curs[d4.z >> 7], 1u);
                recs_mid[p2] = make_int2(s4.z | ((d4.z & 127) << 17), __float_as_int(w4.z));
                unsigned p3 = atomicAdd(&curs[d4.w >> 7], 1u);
                recs_mid[p3] = make_int2(s4.w | ((d4.w & 127) << 17), __float_as_int(w4.w));
            } else {
#pragma unroll
                for (int j = 0; j < 4; j++) {
                    const int ee = e + j;
                    if (ee < e1) {
                        int src = ei[ee];
                        int dst = ei[E + ee];
                        unsigned pos = atomicAdd(&curs[dst >> 7], 1u);
                        recs_mid[pos] = make_int2(src | ((dst & 127) << 17),
                                                  __float_as_int(ew[ee]));
                    }
                }
            }
        }
    } else {
        gemm0_body((int)blockIdx.x - CBC, xs, X, Wt, H, nrows);
    }
}

// ---------------- GEMM1: bf16 agg staged to LDS + BN0+ReLU fused ------------
__global__ __launch_bounds__(256) void k_gemm1(const short* __restrict__ X,
                                               const short* __restrict__ Wt,
                                               const float* __restrict__ prm,
                                               short* __restrict__ H, int nrows) {
    __shared__ short xs[4096];   // 8KB
    const int t = threadIdx.x;
    const int lane = t & 63;
    const int w = t >> 6;
    const int r0 = blockIdx.x * 32;
    const int l15 = lane & 15;
    const int q = lane >> 4;

#pragma unroll
    for (int j = 0; j < 2; j++) {
        const int rbase = w * 8 + j * 4;
        const int row = rbase + q;
        int grow = r0 + row; if (grow >= nrows) grow = nrows - 1;
        const char* gsrc = (const char*)(X + (size_t)grow * 128);
        const int swz = (row & 7) << 4;
#if USE_GLL
        __builtin_amdgcn_global_load_lds(gsrc + (((lane & 15) * 16) ^ swz),
                                         xs + rbase * 128, 16, 0, 0);
#else
        const uint4 v = *reinterpret_cast<const uint4*>(gsrc + (((lane & 15) * 16) ^ swz));
        *reinterpret_cast<uint4*>((char*)xs + rbase * 256 + lane * 16) = v;
#endif
    }
    __syncthreads();

    const int n0 = w * 32;
    const int swzr = (l15 & 7) << 4;

    f32x4 acc[2][2];
#pragma unroll
    for (int mf = 0; mf < 2; mf++)
#pragma unroll
        for (int nf = 0; nf < 2; nf++)
#pragma unroll
            for (int r = 0; r < 4; r++) acc[mf][nf][r] = 0.0f;

#pragma unroll
    for (int ks = 0; ks < 4; ks++) {
        const int kb = ks * 32 + q * 8;
        const int cb = ks * 64 + q * 16;
        const float4 sc0 = *reinterpret_cast<const float4*>(prm + kb);
        const float4 sc1 = *reinterpret_cast<const float4*>(prm + kb + 4);
        const float4 sh0 = *reinterpret_cast<const float4*>(prm + 128 + kb);
        const float4 sh1 = *reinterpret_cast<const float4*>(prm + 128 + kb + 4);
        bf16x8 a[2];
#pragma unroll
        for (int mf = 0; mf < 2; mf++) {
            const char* rb = (const char*)xs + (size_t)(mf * 16 + l15) * 256;
            const bf16x8 ar = *reinterpret_cast<const bf16x8*>(rb + (cb ^ swzr));
            bf16x8 tt;
            tt[0] = f2bf(fmaxf(bf2f(ar[0]) * sc0.x + sh0.x, 0.f));
            tt[1] = f2bf(fmaxf(bf2f(ar[1]) * sc0.y + sh0.y, 0.f));
            tt[2] = f2bf(fmaxf(bf2f(ar[2]) * sc0.z + sh0.z, 0.f));
            tt[3] = f2bf(fmaxf(bf2f(ar[3]) * sc0.w + sh0.w, 0.f));
            tt[4] = f2bf(fmaxf(bf2f(ar[4]) * sc1.x + sh1.x, 0.f));
            tt[5] = f2bf(fmaxf(bf2f(ar[5]) * sc1.y + sh1.y, 0.f));
            tt[6] = f2bf(fmaxf(bf2f(ar[6]) * sc1.z + sh1.z, 0.f));
            tt[7] = f2bf(fmaxf(bf2f(ar[7]) * sc1.w + sh1.w, 0.f));
            a[mf] = tt;
        }
        const bf16x8 b0 = *reinterpret_cast<const bf16x8*>(
            Wt + (size_t)(n0 + l15) * 128 + kb);
        const bf16x8 b1 = *reinterpret_cast<const bf16x8*>(
            Wt + (size_t)(n0 + 16 + l15) * 128 + kb);
        acc[0][0] = __builtin_amdgcn_mfma_f32_16x16x32_bf16(a[0], b0, acc[0][0], 0, 0, 0);
        acc[1][0] = __builtin_amdgcn_mfma_f32_16x16x32_bf16(a[1], b0, acc[1][0], 0, 0, 0);
        acc[0][1] = __builtin_amdgcn_mfma_f32_16x16x32_bf16(a[0], b1, acc[0][1], 0, 0, 0);
        acc[1][1] = __builtin_amdgcn_mfma_f32_16x16x32_bf16(a[1], b1, acc[1][1], 0, 0, 0);
    }

#pragma unroll
    for (int mf = 0; mf < 2; mf++) {
        const int rbase = r0 + mf * 16 + (lane >> 4) * 4;
#pragma unroll
        for (int r = 0; r < 4; r++) {
            const int row = rbase + r;
            if (row < nrows) {
#pragma unroll
                for (int nf = 0; nf < 2; nf++)
                    H[(size_t)row * 128 + n0 + nf * 16 + l15] = f2bf(acc[mf][nf][r]);
            }
        }
    }
}

// -------- phase B: per-bucket scan of HB block counts (4/thread) ------------
__global__ __launch_bounds__(256) void k_phaseB(unsigned* __restrict__ bcnt,
                                                unsigned* __restrict__ btotal,
                                                int HB, int nbuk) {
    __shared__ unsigned lds[256];
    const int k = blockIdx.x;
    const int t = threadIdx.x;
    unsigned v[4];
    unsigned s = 0;
#pragma unroll
    for (int i = 0; i < 4; i++) {
        int j = t * 4 + i;
        v[i] = (j < HB) ? bcnt[(size_t)j * nbuk + k] : 0;
        s += v[i];
    }
    lds[t] = s;
    __syncthreads();
    for (int off = 1; off < 256; off <<= 1) {
        unsigned add = (t >= off) ? lds[t - off] : 0;
        __syncthreads();
        lds[t] += add;
        __syncthreads();
    }
    unsigned run = lds[t] - s;
#pragma unroll
    for (int i = 0; i < 4; i++) {
        int j = t * 4 + i;
        if (j < HB) bcnt[(size_t)j * nbuk + k] = run;
        run += v[i];
    }
    if (t == 255) btotal[k] = lds[255];
}

// ---------------- bucket base scan (single block) ----------------
__global__ __launch_bounds__(256) void k_bsum(const unsigned* __restrict__ btotal,
                                              unsigned* __restrict__ bbase,
                                              int nbuk, int E) {
    __shared__ unsigned lds[256];
    const int t = threadIdx.x;
    unsigned v[4];
    unsigned s = 0;
#pragma unroll
    for (int i = 0; i < 4; i++) {
        int j = t * 4 + i;
        v[i] = (j < nbuk) ? btotal[j] : 0;
        s += v[i];
    }
    lds[t] = s;
    __syncthreads();
    for (int off = 1; off < 256; off <<= 1) {
        unsigned add = (t >= off) ? lds[t - off] : 0;
        __syncthreads();
        lds[t] += add;
        __syncthreads();
    }
    unsigned run = lds[t] - s;
#pragma unroll
    for (int i = 0; i < 4; i++) {
        int j = t * 4 + i;
        if (j < nbuk) bbase[j] = run;
        run += v[i];
    }
    if (t == 255) bbase[nbuk] = (unsigned)E;
}

// ---- phase D: per-bucket dst sort, dinv, rowptr, recs (ew*dinv_dst) --------
__global__ __launch_bounds__(256) void k_phaseD(const int2* __restrict__ recs_mid,
                                                const unsigned* __restrict__ bbase,
                                                float* __restrict__ dinv,
                                                int* __restrict__ rowptr,
                                                int2* __restrict__ recs,
                                                int n, int E) {
    __shared__ unsigned cnt[128], wsum[128], rank[128], sc[128], base[128];
    __shared__ float dloc[128];
    const int k = blockIdx.x;
    const int t = threadIdx.x;
    if (t < 128) { cnt[t] = 0; wsum[t] = 0; rank[t] = 0; }
    __syncthreads();
    const unsigned s0 = bbase[k], s1 = bbase[k + 1];
    for (unsigned i = s0 + t; i < s1; i += 256) {
        int2 r = recs_mid[i];
        int dl = (r.x >> 17) & 127;
        atomicAdd(&cnt[dl], 1u);
        atomicAdd(&wsum[dl], (unsigned)(__int_as_float(r.y) * DEG_SCALE));
    }
    __syncthreads();
    if (t < 128) sc[t] = cnt[t];
    __syncthreads();
    for (int off = 1; off < 128; off <<= 1) {
        unsigned add = (t < 128 && t >= off) ? sc[t - off] : 0;
        __syncthreads();
        if (t < 128) sc[t] += add;
        __syncthreads();
    }
    if (t < 128) {
        unsigned excl = sc[t] - cnt[t];
        base[t] = s0 + excl;
        int dst = k * 128 + t;
        if (dst < n) {
            float dg = (float)wsum[t] * DEG_INV + 1.0f;
            float dv = rsqrtf(dg);
            dloc[t] = dv;
            dinv[dst] = dv;
            rowptr[dst] = (int)(s0 + excl);
        }
    }
    if (k == 0 && t == 0) rowptr[n] = E;
    __syncthreads();
    for (unsigned i = s0 + t; i < s1; i += 256) {
        int2 r = recs_mid[i];
        int dl = (r.x >> 17) & 127;
        unsigned rr = atomicAdd(&rank[dl], 1u);
        float w2 = __int_as_float(r.y) * dloc[dl];     // ew * dinv[dst]
        recs[base[dl] + rr] = make_int2(r.x & 0x1FFFF, __float_as_int(w2));
    }
}

// ------- gather + stats: node per quarter-wave, dinv[src] folded in ---------
__global__ __launch_bounds__(256) void k_gather_stats(const short* __restrict__ h,
                                                      short* __restrict__ aggbf,
                                                      const int* __restrict__ rowptr,
                                                      const int2* __restrict__ recs,
                                                      const float* __restrict__ dinv,
                                                      const float* __restrict__ bias,
                                                      float* __restrict__ partial,
                                                      int n, int nstreams) {
    __shared__ float lsum[4][128], lsq[4][128];
    const int w = threadIdx.x >> 6;
    const int lane = threadIdx.x & 63;
    const int q3 = lane >> 4;            // quarter id: node stream
    const int f8 = (lane & 15) * 8;      // feature slice [f8, f8+8)
    const float4 bv0 = *reinterpret_cast<const float4*>(bias + f8);
    const float4 bv1 = *reinterpret_cast<const float4*>(bias + f8 + 4);
    float s[8], qq[8];
#pragma unroll
    for (int j = 0; j < 8; j++) { s[j] = 0.f; qq[j] = 0.f; }

    for (int node = blockIdx.x * 16 + w * 4 + q3; node < n; node += nstreams) {
        float a[8];
#pragma unroll
        for (int j = 0; j < 8; j++) a[j] = 0.f;
        int e = rowptr[node];
        const int end = rowptr[node + 1];
        for (; e + 4 <= end; e += 4) {
            const int2 r0 = recs[e];
            const int2 r1 = recs[e + 1];
            const int2 r2 = recs[e + 2];
            const int2 r3 = recs[e + 3];
            const float d0 = dinv[r0.x];
            const float d1 = dinv[r1.x];
            const float d2 = dinv[r2.x];
            const float d3 = dinv[r3.x];
            const uint4 v0 = *reinterpret_cast<const uint4*>(h + (size_t)r0.x * 128 + f8);
            const uint4 v1 = *reinterpret_cast<const uint4*>(h + (size_t)r1.x * 128 + f8);
            const uint4 v2 = *reinterpret_cast<const uint4*>(h + (size_t)r2.x * 128 + f8);
            const uint4 v3 = *reinterpret_cast<const uint4*>(h + (size_t)r3.x * 128 + f8);
            const float w0 = __int_as_float(r0.y) * d0;
            const float w1 = __int_as_float(r1.y) * d1;
            const float w2 = __int_as_float(r2.y) * d2;
            const float w3 = __int_as_float(r3.y) * d3;
            a[0] += bflo(v0.x) * w0; a[1] += bfhi(v0.x) * w0;
            a[2] += bflo(v0.y) * w0; a[3] += bfhi(v0.y) * w0;
            a[4] += bflo(v0.z) * w0; a[5] += bfhi(v0.z) * w0;
            a[6] += bflo(v0.w) * w0; a[7] += bfhi(v0.w) * w0;
            a[0] += bflo(v1.x) * w1; a[1] += bfhi(v1.x) * w1;
            a[2] += bflo(v1.y) * w1; a[3] += bfhi(v1.y) * w1;
            a[4] += bflo(v1.z) * w1; a[5] += bfhi(v1.z) * w1;
            a[6] += bflo(v1.w) * w1; a[7] += bfhi(v1.w) * w1;
            a[0] += bflo(v2.x) * w2; a[1] += bfhi(v2.x) * w2;
            a[2] += bflo(v2.y) * w2; a[3] += bfhi(v2.y) * w2;
            a[4] += bflo(v2.z) * w2; a[5] += bfhi(v2.z) * w2;
            a[6] += bflo(v2.w) * w2; a[7] += bfhi(v2.w) * w2;
            a[0] += bflo(v3.x) * w3; a[1] += bfhi(v3.x) * w3;
            a[2] += bflo(v3.y) * w3; a[3] += bfhi(v3.y) * w3;
            a[4] += bflo(v3.z) * w3; a[5] += bfhi(v3.z) * w3;
            a[6] += bflo(v3.w) * w3; a[7] += bfhi(v3.w) * w3;
        }
        for (; e < end; e++) {
            const int2 r = recs[e];
            const float d = dinv[r.x];
            const uint4 v = *reinterpret_cast<const uint4*>(h + (size_t)r.x * 128 + f8);
            const float w0 = __int_as_float(r.y) * d;
            a[0] += bflo(v.x) * w0; a[1] += bfhi(v.x) * w0;
            a[2] += bflo(v.y) * w0; a[3] += bfhi(v.y) * w0;
            a[4] += bflo(v.z) * w0; a[5] += bfhi(v.z) * w0;
            a[6] += bflo(v.w) * w0; a[7] += bfhi(v.w) * w0;
        }
        const float di = dinv[node];
        const float sl = di * di;
        const uint4 hv = *reinterpret_cast<const uint4*>(h + (size_t)node * 128 + f8);
        float o[8];
        o[0] = a[0] + bflo(hv.x) * sl + bv0.x;
        o[1] = a[1] + bfhi(hv.x) * sl + bv0.y;
        o[2] = a[2] + bflo(hv.y) * sl + bv0.z;
        o[3] = a[3] + bfhi(hv.y) * sl + bv0.w;
        o[4] = a[4] + bflo(hv.z) * sl + bv1.x;
        o[5] = a[5] + bfhi(hv.z) * sl + bv1.y;
        o[6] = a[6] + bflo(hv.w) * sl + bv1.z;
        o[7] = a[7] + bfhi(hv.w) * sl + bv1.w;
        bf16x8 ob;
#pragma unroll
        for (int j = 0; j < 8; j++) ob[j] = f2bf(o[j]);
        *reinterpret_cast<bf16x8*>(aggbf + (size_t)node * 128 + f8) = ob;
#pragma unroll
        for (int j = 0; j < 8; j++) { s[j] += o[j]; qq[j] += o[j] * o[j]; }
    }

#pragma unroll
    for (int j = 0; j < 8; j++) {
        s[j] += __shfl_xor(s[j], 16);  s[j] += __shfl_xor(s[j], 32);
        qq[j] += __shfl_xor(qq[j], 16); qq[j] += __shfl_xor(qq[j], 32);
    }
    if (q3 == 0) {
        *reinterpret_cast<float4*>(&lsum[w][f8]) = make_float4(s[0], s[1], s[2], s[3]);
        *reinterpret_cast<float4*>(&lsum[w][f8 + 4]) = make_float4(s[4], s[5], s[6], s[7]);
        *reinterpret_cast<float4*>(&lsq[w][f8]) = make_float4(qq[0], qq[1], qq[2], qq[3]);
        *reinterpret_cast<float4*>(&lsq[w][f8 + 4]) = make_float4(qq[4], qq[5], qq[6], qq[7]);
    }
    __syncthreads();
    const int t = threadIdx.x;
    if (t < 128) {
        float ps = lsum[0][t] + lsum[1][t] + lsum[2][t] + lsum[3][t];
        float pq = lsq[0][t] + lsq[1][t] + lsq[2][t] + lsq[3][t];
        partial[(size_t)blockIdx.x * 256 + t] = ps;
        partial[(size_t)blockIdx.x * 256 + 128 + t] = pq;
    }
}

// -------- stats reduce + BN params in one kernel (block = feature) ----------
__global__ __launch_bounds__(256) void k_stats_bn(const float* __restrict__ partial,
                                                  const float* __restrict__ g,
                                                  const float* __restrict__ beta,
                                                  float* __restrict__ prm,
                                                  int nblk, int n) {
    __shared__ float wsm[4], wqm[4];
    const int f = blockIdx.x;            // 0..127
    const int t = threadIdx.x;
    const int per = nblk / 256;          // 8
    float s = 0.f, q = 0.f;
    for (int i = 0; i < per; i++) {
        int p = t * per + i;
        s += partial[(size_t)p * 256 + f];
        q += partial[(size_t)p * 256 + 128 + f];
    }
#pragma unroll
    for (int off = 1; off < 64; off <<= 1) {
        s += __shfl_xor(s, off);
        q += __shfl_xor(q, off);
    }
    if ((t & 63) == 0) { wsm[t >> 6] = s; wqm[t >> 6] = q; }
    __syncthreads();
    if (t == 0) {
        float S = wsm[0] + wsm[1] + wsm[2] + wsm[3];
        float Q = wqm[0] + wqm[1] + wqm[2] + wqm[3];
        float inv_n = 1.0f / (float)n;
        float mu = S * inv_n;
        float var = Q * inv_n - mu * mu;
        float sc = rsqrtf(var + BN_EPS) * g[f];
        prm[f] = sc;
        prm[128 + f] = beta[f] - mu * sc;
    }
}

// ---------------- final BN apply + ReLU (bf16 agg -> f32 out) ----------------
__global__ __launch_bounds__(256) void k_bn_relu(const short* __restrict__ xbf,
                                                 float* __restrict__ y,
                                                 const float* __restrict__ prm, int n) {
    int idx = blockIdx.x * blockDim.x + threadIdx.x;
    const int total = n * 16;
    for (; idx < total; idx += gridDim.x * blockDim.x) {
        int node = idx >> 4;
        int f8 = (idx & 15) * 8;
        const uint4 v = *reinterpret_cast<const uint4*>(xbf + (size_t)node * 128 + f8);
        const float4 sc0 = *reinterpret_cast<const float4*>(prm + f8);
        const float4 sc1 = *reinterpret_cast<const float4*>(prm + f8 + 4);
        const float4 sh0 = *reinterpret_cast<const float4*>(prm + 128 + f8);
        const float4 sh1 = *reinterpret_cast<const float4*>(prm + 128 + f8 + 4);
        float4 o0, o1;
        o0.x = fmaxf(bflo(v.x) * sc0.x + sh0.x, 0.f);
        o0.y = fmaxf(bfhi(v.x) * sc0.y + sh0.y, 0.f);
        o0.z = fmaxf(bflo(v.y) * sc0.z + sh0.z, 0.f);
        o0.w = fmaxf(bfhi(v.y) * sc0.w + sh0.w, 0.f);
        o1.x = fmaxf(bflo(v.z) * sc1.x + sh1.x, 0.f);
        o1.y = fmaxf(bfhi(v.z) * sc1.y + sh1.y, 0.f);
        o1.z = fmaxf(bflo(v.w) * sc1.z + sh1.z, 0.f);
        o1.w = fmaxf(bfhi(v.w) * sc1.w + sh1.w, 0.f);
        float* yp = y + (size_t)node * 128 + f8;
        *reinterpret_cast<float4*>(yp) = o0;
        *reinterpret_cast<float4*>(yp + 4) = o1;
    }
}

extern "C" void kernel_launch(void* const* d_in, const int* in_sizes, int n_in,
                              void* d_out, int out_size, void* d_ws, size_t ws_size,
                              hipStream_t stream) {
    const float* x   = (const float*)d_in[0];
    const int*   ei  = (const int*)d_in[1];
    const float* ew  = (const float*)d_in[2];
    const float* W0  = (const float*)d_in[3];
    const float* b0  = (const float*)d_in[4];
    const float* g0  = (const float*)d_in[5];
    const float* be0 = (const float*)d_in[6];
    const float* W1  = (const float*)d_in[7];
    const float* b1  = (const float*)d_in[8];
    const float* g1  = (const float*)d_in[9];
    const float* be1 = (const float*)d_in[10];
    float* out = (float*)d_out;

    const int N = in_sizes[0] / FIN;          // 100000
    const int E = in_sizes[2];                // 1600000
    const int NBUK = (N + 127) >> 7;          // 782
    const int HB = 1024;                      // fine-grained hist blocks
    const int CHUNKH = (E + HB - 1) / HB;     // 1563
    const int CBC = 256;                      // phaseC blocks
    const int SUB = HB / CBC;                 // 4
    const int CHUNKC = CHUNKH * SUB;          // 6252
    const int GB = 2048;                      // gather grid

    // workspace layout
    short* aggbf    = (short*)d_ws;                          // [N,128] bf16
    short* hbf      = aggbf + (size_t)N * 128;               // [N,128] bf16
    int2*  recs     = (int2*)(hbf + (size_t)N * 128);        // [E]
    int2*  recs_mid = recs + E;                              // [E]
    unsigned* bcnt  = (unsigned*)(recs_mid + E);             // [HB*NBUK]
    unsigned* btotal= bcnt + (size_t)HB * NBUK;              // [NBUK]
    unsigned* bbase = btotal + NBUK;                         // [NBUK+1]
    float* dinv     = (float*)(bbase + NBUK + 1);            // [N]
    int*   rowptr   = (int*)(dinv + N);                      // [N+1]
    float* prm      = (float*)(rowptr + N + 1);              // 256
    float* partial  = prm + 256;                             // [GB*256]

    // Wt staged in d_out (scratch until final bn_relu overwrites)
    short* Wt0 = (short*)d_out;            // [128][256] bf16
    short* Wt1 = Wt0 + 256 * 128;          // [128][128] bf16

    const int gemm_blocks = (N + 31) / 32;

    // ---- hist + weight prep ----
    k_histprep<<<HB + 192, 256, 0, stream>>>(ei, E, HB, CHUNKH, NBUK, bcnt,
                                             W0, W1, Wt0, Wt1);
    k_phaseB<<<NBUK, 256, 0, stream>>>(bcnt, btotal, HB, NBUK);
    k_bsum<<<1, 256, 0, stream>>>(btotal, bbase, NBUK, E);

    // ---- fused bucket-scatter || gemm0 ----
    k_phaseCG<<<CBC + gemm_blocks, 256, 0, stream>>>(ei, ew, E, CHUNKC, NBUK, SUB,
                                                     bcnt, bbase, recs_mid, CBC,
                                                     x, Wt0, hbf, N);
    k_phaseD<<<NBUK, 256, 0, stream>>>(recs_mid, bbase, dinv, rowptr, recs, N, E);

    // ---- layer 0 ----
    k_gather_stats<<<GB, 256, 0, stream>>>(hbf, aggbf, rowptr, recs, dinv, b0,
                                           partial, N, GB * 16);
    k_stats_bn<<<128, 256, 0, stream>>>(partial, g0, be0, prm, GB, N);

    // ---- layer 1 ----
    k_gemm1<<<gemm_blocks, 256, 0, stream>>>(aggbf, Wt1, prm, hbf, N);
    k_gather_stats<<<GB, 256, 0, stream>>>(hbf, aggbf, rowptr, recs, dinv, b1,
                                           partial, N, GB * 16);
    k_stats_bn<<<128, 256, 0, stream>>>(partial, g1, be1, prm, GB, N);
    k_bn_relu<<<2048, 256, 0, stream>>>(aggbf, out, prm, N);
}